// Round 3
// baseline (5059.541 us; speedup 1.0000x reference)
//
#include <hip/hip_runtime.h>
#include <hip/hip_bf16.h>

#define NV 100000
#define EPSB 1e-5f

typedef unsigned short u16;
typedef unsigned int u32;

__device__ __forceinline__ float bflo(u32 u) {
  union { u32 i; float f; } v; v.i = u << 16; return v.f;
}
__device__ __forceinline__ float bfhi(u32 u) {
  union { u32 i; float f; } v; v.i = u & 0xffff0000u; return v.f;
}
__device__ __forceinline__ float bf2f(u16 u) {
  union { u32 i; float f; } v; v.i = ((u32)u) << 16; return v.f;
}
__device__ __forceinline__ u16 f2bf(float f) {
  union { float f; u32 i; } v; v.f = f;
  u32 r = v.i + 0x7fffu + ((v.i >> 16) & 1u);  // RNE
  return (u16)(r >> 16);
}
__device__ __forceinline__ u32 pack2(float x, float y) {
  return ((u32)f2bf(x)) | (((u32)f2bf(y)) << 16);
}
// hw packed f32->bf16x2 convert (1 VALU op), lo=src0 hi=src1
__device__ __forceinline__ u32 cvtpk(float x, float y) {
  u32 r;
  asm("v_cvt_pk_bf16_f32 %0, %1, %2" : "=v"(r) : "v"(x), "v"(y));
  return r;
}
// uniform broadcast from a lane: v_readlane -> SGPR operand (free in FMA)
__device__ __forceinline__ float bcastf(float v, int l) {
  union { float f; int i; } a; a.f = v;
  union { int i; float f; } b; b.i = __builtin_amdgcn_readlane(a.i, l);
  return b.f;
}
__device__ __forceinline__ float asf(u32 u) {
  union { u32 i; float f; } v; v.i = u; return v.f;
}

// ---------------------------------------------------------------------------
// K0: detect key_mask element width (int32 vs byte-bool).
// ---------------------------------------------------------------------------
__global__ void k0_detect(const u32* __restrict__ km, int* __restrict__ flag) {
  int bad = 0;
  for (int i = threadIdx.x; i < 4096; i += 256) {
    u32 v = km[i];
    bad |= (v != 0u && v != 1u && v != 0x3F800000u) ? 1 : 0;
  }
  unsigned long long m = __ballot(bad != 0);
  __shared__ int sbad[4];
  if ((threadIdx.x & 63) == 0) sbad[threadIdx.x >> 6] = (m != 0ull);
  __syncthreads();
  if (threadIdx.x == 0) flag[0] = !(sbad[0] | sbad[1] | sbad[2] | sbad[3]);
}

// ---------------------------------------------------------------------------
// Kprep: P[m][c] = coords[m,:] . k_pos_w[c,:]   (pos-emb projection table)
// ---------------------------------------------------------------------------
__global__ __launch_bounds__(256) void k_prep(
    const float* __restrict__ coords, const float* __restrict__ kpw,
    float* __restrict__ P)
{
  const int t = blockIdx.x*256 + threadIdx.x;   // grid 1024 -> 262144 threads
  const int c = t & 63;                          // stride % 64 == 0 -> constant
  const float w0 = kpw[c*3], w1 = kpw[c*3+1], w2 = kpw[c*3+2];
  for (int e = t; e < NV*64; e += 262144) {
    int m = e >> 6;
    float c0 = coords[m*3], c1 = coords[m*3+1], c2 = coords[m*3+2];
    P[e] = fmaf(w0, c0, fmaf(w1, c1, w2*c2));
  }
}

// ---------------------------------------------------------------------------
// K1: gather attention.  1024-thread block = 16 waves, one voxel per wave.
// lane roles: cl=lane&31, kh=lane>>5.
//   gather/pe/pack: lane handles channels (2cl,2cl+1) of keys kh*16..kh*16+15
//   score:          lane handles key cl, heads kh and kh+2
//   PV/ctx/wo:      lane = single channel (lane)
// LDS: 48KB weights + 16 x 5808B per-wave {KFp bf16[32][33u32], QKp bf16[4][33u32], S f32[4][66]}
// ---------------------------------------------------------------------------
__global__ __launch_bounds__(1024) void k1_attn(
    const float* __restrict__ vf, const float* __restrict__ coords,
    const int* __restrict__ kidx, const void* __restrict__ kmaskv,
    const int* __restrict__ mflag, const float* __restrict__ P,
    const float* __restrict__ wq, const float* __restrict__ bq,
    const float* __restrict__ wk,
    const float* __restrict__ wv, const float* __restrict__ bv,
    const float* __restrict__ wo, const float* __restrict__ bo,
    const float* __restrict__ qpw, const float* __restrict__ qpb,
    const float* __restrict__ kpb,
    float* __restrict__ x1pre, float* __restrict__ stats)
{
  extern __shared__ char smem[];
  float* WQT = (float*)smem;            // [c][i] = wq[i][c], fp32 16KB
  float* WKN = WQT + 4096;              // [i][c] natural,    fp32 16KB
  u32*   WVP = (u32*)(WKN + 4096);      // [c2][i] bf16 pair, 8KB
  u32*   WOP = WVP + 2048;              // [c2][i] bf16 pair, 8KB
  const int tid = threadIdx.x, wid = tid >> 6, lane = tid & 63;

  for (int t = tid; t < 4096; t += 1024) {
    int i = t >> 6, c = t & 63;
    WQT[c*64 + i] = wq[t];
    WKN[t]        = wk[t];
  }
  for (int t = tid; t < 2048; t += 1024) {
    int c2 = t >> 6, i = t & 63;
    WVP[t] = pack2(wv[i*64 + 2*c2], wv[i*64 + 2*c2 + 1]);
    WOP[t] = pack2(wo[i*64 + 2*c2], wo[i*64 + 2*c2 + 1]);
  }
  __syncthreads();

  u32* wbase = (u32*)(smem + 49152) + wid * 1452;
  u32*   KFp = wbase;            // [32][33] u32 bf16-pairs
  u32*   QKp = wbase + 1056;     // [4][33]  u32 bf16-pairs
  float* S   = (float*)(wbase + 1188);  // [4][66] f32

  const int cl = lane & 31, kh = lane >> 5, hh = lane >> 4;
  const int ca = 2*cl;  // gather channel pair (ca, ca+1)
  const float qp0 = qpw[lane*3], qp1 = qpw[lane*3+1], qp2 = qpw[lane*3+2], qpbl = qpb[lane];
  const float kpbA = kpb[ca], kpbB = kpb[ca+1];
  const float bql = bq[lane], bvl = bv[lane], bol = bo[lane];
  const u32 pvsh = ((lane & 1) ^ 1) << 4;   // PV in-pair select shift
  const int mode4 = mflag[0];
  const u32* km32 = (const u32*)kmaskv;
  const unsigned char* km8 = (const unsigned char*)kmaskv;
  float ssum = 0.f, ssq = 0.f;

  for (int n = blockIdx.x*16 + wid; n < NV; n += 4096) {
    // ---- per-voxel scalars ----
    const float cn0 = coords[n*3], cn1 = coords[n*3+1], cn2 = coords[n*3+2];
    u32 mk;                                           // mask for key cl
    if (mode4) mk = (km32[n*32 + cl] != 0u);
    else       mk = (km8[n*32 + cl]  != 0u);
    const float vfl = vf[(size_t)n*64 + lane];
    const float2 Pn = *(const float2*)(P + (size_t)n*64 + ca);
    const float pnA = Pn.x - kpbA, pnB = Pn.y - kpbB;

    // key indices for this lane's half (uniform within half)
    union { int4 v[4]; int s[16]; } iu;
    {
      const int4* kp4 = (const int4*)(kidx + (size_t)n*32 + kh*16);
      iu.v[0] = kp4[0]; iu.v[1] = kp4[1]; iu.v[2] = kp4[2]; iu.v[3] = kp4[3];
    }

    // ---- gather + pos-emb + bf16-pack -> KFp, two batches of 8 keys ----
    #pragma unroll
    for (int b = 0; b < 2; ++b) {
      float2 g[8], p[8];
      #pragma unroll
      for (int k = 0; k < 8; ++k) {
        const size_t off = (size_t)iu.s[b*8+k]*64 + ca;
        g[k] = *(const float2*)(vf + off);
        p[k] = *(const float2*)(P + off);
      }
      #pragma unroll
      for (int k = 0; k < 8; ++k) {
        float kfA = g[k].x + fmaxf(p[k].x - pnA, 0.f);
        float kfB = g[k].y + fmaxf(p[k].y - pnB, 0.f);
        KFp[(kh*16 + b*8 + k)*33 + cl] = cvtpk(kfA, kfB);
      }
    }

    // ---- query = vf + relu(coords @ qpw^T + qpb) ----
    float query = vfl + fmaxf(fmaf(qp0,cn0,fmaf(qp1,cn1,fmaf(qp2,cn2,qpbl))), 0.f);

    // ---- q = Wq query + bq (lane = i), 4 chains ----
    float qa0 = bql, qa1 = 0.f, qa2 = 0.f, qa3 = 0.f;
    #pragma unroll
    for (int c = 0; c < 16; ++c) {
      qa0 = fmaf(WQT[(c   )*64+lane], bcastf(query, c   ), qa0);
      qa1 = fmaf(WQT[(c+16)*64+lane], bcastf(query, c+16), qa1);
      qa2 = fmaf(WQT[(c+32)*64+lane], bcastf(query, c+32), qa2);
      qa3 = fmaf(WQT[(c+48)*64+lane], bcastf(query, c+48), qa3);
    }
    const float qacc = (qa0+qa1) + (qa2+qa3);

    // ---- qk[h][c] = (Wk_h^T q_h)[c] / 4 (lane = c), 4 chains ----
    float qkh0=0.f, qkh1=0.f, qkh2=0.f, qkh3=0.f;
    #pragma unroll
    for (int i = 0; i < 16; ++i) {
      qkh0 = fmaf(WKN[(i   )*64+lane], bcastf(qacc, i   ), qkh0);
      qkh1 = fmaf(WKN[(i+16)*64+lane], bcastf(qacc, i+16), qkh1);
      qkh2 = fmaf(WKN[(i+32)*64+lane], bcastf(qacc, i+32), qkh2);
      qkh3 = fmaf(WKN[(i+48)*64+lane], bcastf(qacc, i+48), qkh3);
    }
    // pack qk pairs: even lane packs (c, c+1)
    {
      float t0 = __shfl_down(qkh0, 1), t1 = __shfl_down(qkh1, 1);
      float t2 = __shfl_down(qkh2, 1), t3 = __shfl_down(qkh3, 1);
      if ((lane & 1) == 0) {
        int j = lane >> 1;
        QKp[      j] = cvtpk(qkh0*0.25f, t0*0.25f);
        QKp[ 33 + j] = cvtpk(qkh1*0.25f, t1*0.25f);
        QKp[ 66 + j] = cvtpk(qkh2*0.25f, t2*0.25f);
        QKp[ 99 + j] = cvtpk(qkh3*0.25f, t3*0.25f);
      }
    }

    // ---- scores: lane -> key cl, heads kh and kh+2 ----
    float s00=0.f, s01=0.f, s10=0.f, s11=0.f;
    #pragma unroll
    for (int c2 = 0; c2 < 32; ++c2) {
      u32 kp = KFp[cl*33 + c2];
      u32 q0 = QKp[ kh   *33 + c2];
      u32 q1 = QKp[(kh+2)*33 + c2];
      float k0 = bflo(kp), k1 = bfhi(kp);
      s00 = fmaf(bflo(q0), k0, s00); s01 = fmaf(bfhi(q0), k1, s01);
      s10 = fmaf(bflo(q1), k0, s10); s11 = fmaf(bfhi(q1), k1, s11);
    }
    float sc0 = s00 + s01, sc1 = s10 + s11;
    if (mk) { sc0 = -1e30f; sc1 = -1e30f; }

    // ---- softmax over k within each 32-lane half ----
    float m0 = sc0, m1 = sc1;
    #pragma unroll
    for (int off = 16; off; off >>= 1) {
      m0 = fmaxf(m0, __shfl_xor(m0, off));
      m1 = fmaxf(m1, __shfl_xor(m1, off));
    }
    float p0 = __expf(sc0 - m0), p1 = __expf(sc1 - m1);
    float s0 = p0, s1 = p1;
    #pragma unroll
    for (int off = 16; off; off >>= 1) {
      s0 += __shfl_xor(s0, off);
      s1 += __shfl_xor(s1, off);
    }
    const float a0 = p0 / s0, a1 = p1 / s1;  // attn[kh][cl], attn[kh+2][cl]

    // ---- S[h][c] = sum_k attn[h][k]*kf[k][c]  (lane = channel) ----
    float sa0=0.f, sa1=0.f, sa2=0.f, sa3=0.f;
    #pragma unroll
    for (int k2 = 0; k2 < 32; ++k2) {
      u32 kp = KFp[k2*33 + (lane>>1)];
      float kfv = asf((kp << pvsh) & 0xffff0000u);
      sa0 = fmaf(bcastf(a0, k2),    kfv, sa0);
      sa1 = fmaf(bcastf(a0, k2+32), kfv, sa1);
      sa2 = fmaf(bcastf(a1, k2),    kfv, sa2);
      sa3 = fmaf(bcastf(a1, k2+32), kfv, sa3);
    }
    S[       lane] = sa0;
    S[ 66  + lane] = sa1;
    S[132  + lane] = sa2;
    S[198  + lane] = sa3;

    // ---- ctx[i] = Wv_h S[h] + bv  (lane = i, h = i>>4) ----
    float ca0 = bvl, ca1 = 0.f;
    #pragma unroll
    for (int c2 = 0; c2 < 16; ++c2) {
      u32 wp0 = WVP[ c2    *64 + lane];
      u32 wp1 = WVP[(c2+16)*64 + lane];
      ca0 = fmaf(bflo(wp0), S[hh*66 + 2*c2     ], ca0);
      ca0 = fmaf(bfhi(wp0), S[hh*66 + 2*c2 +  1], ca0);
      ca1 = fmaf(bflo(wp1), S[hh*66 + 2*c2 + 32], ca1);
      ca1 = fmaf(bfhi(wp1), S[hh*66 + 2*c2 + 33], ca1);
    }
    const float cacc = ca0 + ca1;

    // ---- attend = Wo ctx + bo ----
    float oa0 = bol, oa1 = 0.f;
    #pragma unroll
    for (int c2 = 0; c2 < 16; ++c2) {
      u32 wp0 = WOP[ c2    *64 + lane];
      u32 wp1 = WOP[(c2+16)*64 + lane];
      oa0 = fmaf(bflo(wp0), bcastf(cacc, 2*c2     ), oa0);
      oa0 = fmaf(bfhi(wp0), bcastf(cacc, 2*c2 +  1), oa0);
      oa1 = fmaf(bflo(wp1), bcastf(cacc, 2*c2 + 32), oa1);
      oa1 = fmaf(bfhi(wp1), bcastf(cacc, 2*c2 + 33), oa1);
    }
    const float aacc = oa0 + oa1;

    float x1 = vfl + aacc;
    x1pre[(size_t)n*64 + lane] = x1;
    ssum += x1; ssq = fmaf(x1, x1, ssq);
  }

  // ---- block-reduce BN1 partials ----
  __syncthreads();
  float* red = (float*)smem;
  red[wid*64 + lane] = ssum;
  red[1024 + wid*64 + lane] = ssq;
  __syncthreads();
  if (wid == 0) {
    float t1 = 0.f, t2 = 0.f;
    #pragma unroll
    for (int w = 0; w < 16; ++w) { t1 += red[w*64+lane]; t2 += red[1024+w*64+lane]; }
    atomicAdd(&stats[lane], t1);
    atomicAdd(&stats[64+lane], t2);
  }
}

// ---------------------------------------------------------------------------
// K3: x1 = BN1(x1pre); x2pre = x1 + FFN(x1); BN2 partials.  1024 threads.
// ---------------------------------------------------------------------------
__global__ __launch_bounds__(1024) void k3_ffn(
    const float* __restrict__ x1pre, float* __restrict__ stats,
    const float* __restrict__ g1, const float* __restrict__ b1,
    const float* __restrict__ l1w, const float* __restrict__ l1b,
    const float* __restrict__ l2w, const float* __restrict__ l2b,
    float* __restrict__ x2pre)
{
  extern __shared__ char smem[];
  u16* L1T = (u16*)smem;                      // [c][f]
  u32* L2P = (u32*)(smem + 32768);            // [f2][c]
  const int tid = threadIdx.x, wid = tid >> 6, lane = tid & 63;

  for (int t = tid; t < 16384; t += 1024) {
    int f = t >> 6, c = t & 63;
    L1T[c*256 + f] = f2bf(l1w[t]);
  }
  for (int t = tid; t < 8192; t += 1024) {
    int c = t >> 7, f2 = t & 127;
    float2 w2 = *(const float2*)&l2w[c*256 + f2*2];
    L2P[f2*64 + c] = pack2(w2.x, w2.y);
  }
  __syncthreads();

  const float mean = stats[lane] * (1.f/NV);
  const float var  = stats[64+lane] * (1.f/NV) - mean*mean;
  const float sc   = rsqrtf(var + EPSB) * g1[lane];
  const float sh   = b1[lane] - mean * sc;
  const float4 l1b4 = *(const float4*)&l1b[4*lane];
  const float l2bl = l2b[lane];
  float ssum = 0.f, ssq = 0.f;

  const int stride = gridDim.x << 4;
  for (int n = blockIdx.x*16 + wid; n < NV; n += stride) {
    float x1 = x1pre[(size_t)n*64+lane] * sc + sh;

    float h0 = l1b4.x, h1 = l1b4.y, h2 = l1b4.z, h3 = l1b4.w;
    #pragma unroll
    for (int c = 0; c < 64; ++c) {
      float xv = bcastf(x1, c);
      uint2 wp = *(const uint2*)&L1T[c*256 + 4*lane];
      h0 = fmaf(bflo(wp.x), xv, h0);
      h1 = fmaf(bfhi(wp.x), xv, h1);
      h2 = fmaf(bflo(wp.y), xv, h2);
      h3 = fmaf(bfhi(wp.y), xv, h3);
    }
    h0 = fmaxf(h0,0.f); h1 = fmaxf(h1,0.f); h2 = fmaxf(h2,0.f); h3 = fmaxf(h3,0.f);

    float ff = l2bl;
    #pragma unroll
    for (int f2 = 0; f2 < 128; ++f2) {
      const int sl = f2 >> 1;
      float ha, hbv;
      if ((f2 & 1) == 0) { ha = bcastf(h0, sl); hbv = bcastf(h1, sl); }
      else               { ha = bcastf(h2, sl); hbv = bcastf(h3, sl); }
      u32 wp = L2P[f2*64 + lane];
      ff = fmaf(bflo(wp), ha,  ff);
      ff = fmaf(bfhi(wp), hbv, ff);
    }

    float x2 = x1 + ff;
    x2pre[(size_t)n*64+lane] = x2;
    ssum += x2; ssq = fmaf(x2, x2, ssq);
  }

  __syncthreads();
  float* red = (float*)smem;
  red[wid*64 + lane] = ssum;
  red[1024 + wid*64 + lane] = ssq;
  __syncthreads();
  if (wid == 0) {
    float t1 = 0.f, t2 = 0.f;
    #pragma unroll
    for (int w = 0; w < 16; ++w) { t1 += red[w*64+lane]; t2 += red[1024+w*64+lane]; }
    atomicAdd(&stats[128+lane], t1);
    atomicAdd(&stats[192+lane], t2);
  }
}

// ---------------------------------------------------------------------------
// K4: x2 = BN2(x2pre); outpre = x2 @ out_w^T + out_b; BN3 partials.
// ---------------------------------------------------------------------------
__global__ __launch_bounds__(256) void k4_out(
    const float* __restrict__ x2pre, float* __restrict__ stats,
    const float* __restrict__ g2, const float* __restrict__ b2,
    const float* __restrict__ outw, const float* __restrict__ outb,
    float* __restrict__ outpre)
{
  extern __shared__ char smem[];
  u16* WT = (u16*)smem;                       // [c][o]
  const int tid = threadIdx.x, wid = tid >> 6, lane = tid & 63;
  for (int t = tid; t < 4096; t += 256) {
    int o = t >> 6, c = t & 63;
    WT[c*64+o] = f2bf(outw[t]);
  }
  __syncthreads();

  const float mean = stats[128+lane] * (1.f/NV);
  const float var  = stats[192+lane] * (1.f/NV) - mean*mean;
  const float sc   = rsqrtf(var + EPSB) * g2[lane];
  const float sh   = b2[lane] - mean * sc;
  const float obl  = outb[lane];
  float ssum = 0.f, ssq = 0.f;

  const int stride = gridDim.x << 2;
  for (int n = blockIdx.x*4 + wid; n < NV; n += stride) {
    float x2 = x2pre[(size_t)n*64+lane] * sc + sh;
    float a0 = obl, a1 = 0.f;
    #pragma unroll
    for (int c = 0; c < 32; ++c) {
      a0 = fmaf(bf2f(WT[(c   )*64+lane]), bcastf(x2, c   ), a0);
      a1 = fmaf(bf2f(WT[(c+32)*64+lane]), bcastf(x2, c+32), a1);
    }
    float acc = a0 + a1;
    outpre[(size_t)n*64+lane] = acc;
    ssum += acc; ssq = fmaf(acc, acc, ssq);
  }

  __syncthreads();
  float* red = (float*)smem;
  red[wid*64+lane] = ssum;
  red[256 + wid*64 + lane] = ssq;
  __syncthreads();
  if (wid == 0) {
    float t1 = 0.f, t2 = 0.f;
    #pragma unroll
    for (int w = 0; w < 4; ++w) { t1 += red[w*64+lane]; t2 += red[256+w*64+lane]; }
    atomicAdd(&stats[256+lane], t1);
    atomicAdd(&stats[320+lane], t2);
  }
}

// ---------------------------------------------------------------------------
// K5: out = relu(BN3(outpre))
// ---------------------------------------------------------------------------
__global__ __launch_bounds__(256) void k5_fin(
    const float* __restrict__ outpre, const float* __restrict__ stats,
    const float* __restrict__ g3, const float* __restrict__ b3,
    float* __restrict__ out)
{
  const int t = blockIdx.x*256 + threadIdx.x;     // 131072 threads
  const int c0 = (t*4) & 63;
  float sc[4], sh[4];
  #pragma unroll
  for (int j = 0; j < 4; ++j) {
    int c = c0 + j;
    float mean = stats[256+c] * (1.f/NV);
    float var  = stats[320+c] * (1.f/NV) - mean*mean;
    sc[j] = rsqrtf(var + EPSB) * g3[c];
    sh[j] = b3[c] - mean*sc[j];
  }
  for (int i = t; i < NV*16; i += 131072) {
    float4 v = *(const float4*)&outpre[(size_t)i*4];
    v.x = fmaxf(fmaf(v.x, sc[0], sh[0]), 0.f);
    v.y = fmaxf(fmaf(v.y, sc[1], sh[1]), 0.f);
    v.z = fmaxf(fmaf(v.z, sc[2], sh[2]), 0.f);
    v.w = fmaxf(fmaf(v.w, sc[3], sh[3]), 0.f);
    *(float4*)&out[(size_t)i*4] = v;
  }
}

extern "C" void kernel_launch(void* const* d_in, const int* in_sizes, int n_in,
                              void* d_out, int out_size, void* d_ws, size_t ws_size,
                              hipStream_t stream) {
  (void)in_sizes; (void)n_in; (void)out_size; (void)ws_size;
  const float* vf     = (const float*)d_in[0];
  const float* coords = (const float*)d_in[1];
  const int*   kidx   = (const int*)d_in[2];
  const void*  kmask  = d_in[3];
  const float* wq  = (const float*)d_in[4];  const float* bq  = (const float*)d_in[5];
  const float* wk  = (const float*)d_in[6];  /* bk cancels in softmax */
  const float* wv  = (const float*)d_in[8];  const float* bv  = (const float*)d_in[9];
  const float* wo  = (const float*)d_in[10]; const float* bo  = (const float*)d_in[11];
  const float* qpw = (const float*)d_in[12]; const float* qpb = (const float*)d_in[13];
  const float* kpw = (const float*)d_in[14]; const float* kpb = (const float*)d_in[15];
  const float* g1  = (const float*)d_in[16]; const float* b1  = (const float*)d_in[17];
  const float* g2  = (const float*)d_in[18]; const float* b2  = (const float*)d_in[19];
  const float* l1w = (const float*)d_in[20]; const float* l1b = (const float*)d_in[21];
  const float* l2w = (const float*)d_in[22]; const float* l2b = (const float*)d_in[23];
  const float* outw= (const float*)d_in[24]; const float* outb= (const float*)d_in[25];
  const float* g3  = (const float*)d_in[26]; const float* b3  = (const float*)d_in[27];

  float* wsf    = (float*)d_ws;
  float* x1pre  = wsf;                       // [N*64]
  float* x2pre  = wsf + (size_t)NV*64;       // [N*64]; aliases P before K3
  float* P      = x2pre;                     // pos-emb table, dead once K1 ends
  float* outpre = x1pre;                     // alias: x1pre dead after K3
  float* stats  = wsf + (size_t)2*NV*64;     // [384]
  int*   mflag  = (int*)(stats + 384);

  hipMemsetAsync(stats, 0, 384*sizeof(float), stream);

  (void)hipFuncSetAttribute((const void*)k1_attn, hipFuncAttributeMaxDynamicSharedMemorySize, 142080);
  (void)hipFuncSetAttribute((const void*)k3_ffn,  hipFuncAttributeMaxDynamicSharedMemorySize, 65536);

  k0_detect<<<1, 256, 0, stream>>>((const u32*)kmask, mflag);
  k_prep<<<1024, 256, 0, stream>>>(coords, kpw, P);
  k1_attn<<<256, 1024, 142080, stream>>>(vf, coords, kidx, kmask, mflag, P,
      wq, bq, wk, wv, bv, wo, bo, qpw, qpb, kpb, x1pre, stats);
  k3_ffn<<<512, 1024, 65536, stream>>>(x1pre, stats, g1, b1, l1w, l1b, l2w, l2b, x2pre);
  k4_out<<<2048, 256, 8192, stream>>>(x2pre, stats, g2, b2, outw, outb, outpre);
  k5_fin<<<512, 256, 0, stream>>>(outpre, stats, g3, b3, (float*)d_out);
}

// Round 4
// 4079.765 us; speedup vs baseline: 1.2402x; 1.2402x over previous
//
#include <hip/hip_runtime.h>
#include <hip/hip_bf16.h>

#define NV 100000
#define EPSB 1e-5f

typedef unsigned short u16;
typedef unsigned int u32;

__device__ __forceinline__ float bflo(u32 u) {
  union { u32 i; float f; } v; v.i = u << 16; return v.f;
}
__device__ __forceinline__ float bfhi(u32 u) {
  union { u32 i; float f; } v; v.i = u & 0xffff0000u; return v.f;
}
__device__ __forceinline__ float bf2f(u16 u) {
  union { u32 i; float f; } v; v.i = ((u32)u) << 16; return v.f;
}
__device__ __forceinline__ u16 f2bf(float f) {
  union { float f; u32 i; } v; v.f = f;
  u32 r = v.i + 0x7fffu + ((v.i >> 16) & 1u);  // RNE
  return (u16)(r >> 16);
}
__device__ __forceinline__ u32 pack2(float x, float y) {
  return ((u32)f2bf(x)) | (((u32)f2bf(y)) << 16);
}
// hw packed f32->bf16x2 convert (1 VALU op), lo=src0 hi=src1
__device__ __forceinline__ u32 cvtpk(float x, float y) {
  u32 r;
  asm("v_cvt_pk_bf16_f32 %0, %1, %2" : "=v"(r) : "v"(x), "v"(y));
  return r;
}
// uniform broadcast from a lane: v_readlane -> SGPR operand (free in FMA)
__device__ __forceinline__ float bcastf(float v, int l) {
  union { float f; int i; } a; a.f = v;
  union { int i; float f; } b; b.i = __builtin_amdgcn_readlane(a.i, l);
  return b.f;
}
__device__ __forceinline__ float asf(u32 u) {
  union { u32 i; float f; } v; v.i = u; return v.f;
}

// ---------------------------------------------------------------------------
// K0: detect key_mask element width (int32 vs byte-bool).
// ---------------------------------------------------------------------------
__global__ void k0_detect(const u32* __restrict__ km, int* __restrict__ flag) {
  int bad = 0;
  for (int i = threadIdx.x; i < 4096; i += 256) {
    u32 v = km[i];
    bad |= (v != 0u && v != 1u && v != 0x3F800000u) ? 1 : 0;
  }
  unsigned long long m = __ballot(bad != 0);
  __shared__ int sbad[4];
  if ((threadIdx.x & 63) == 0) sbad[threadIdx.x >> 6] = (m != 0ull);
  __syncthreads();
  if (threadIdx.x == 0) flag[0] = !(sbad[0] | sbad[1] | sbad[2] | sbad[3]);
}

// ---------------------------------------------------------------------------
// Kprep: P[m][c] = coords[m,:] . k_pos_w[c,:]
// ---------------------------------------------------------------------------
__global__ __launch_bounds__(256) void k_prep(
    const float* __restrict__ coords, const float* __restrict__ kpw,
    float* __restrict__ P)
{
  const int t = blockIdx.x*256 + threadIdx.x;   // grid 1024 -> 262144 threads
  const int c = t & 63;                          // constant per thread
  const float w0 = kpw[c*3], w1 = kpw[c*3+1], w2 = kpw[c*3+2];
  for (int e = t; e < NV*64; e += 262144) {
    int m = e >> 6;
    float c0 = coords[m*3], c1 = coords[m*3+1], c2 = coords[m*3+2];
    P[e] = fmaf(w0, c0, fmaf(w1, c1, w2*c2));
  }
}

// ---------------------------------------------------------------------------
// K1: gather attention.  512-thread block = 8 waves, one voxel per wave.
// All weights bf16-packed in LDS (32KB) + 8 x 5808B per-wave scratch = 79.2KB
// -> 2 blocks/CU = 4 waves/EU (50% occupancy). VGPR cap 128 (no spill, ~80).
// ---------------------------------------------------------------------------
__global__ __launch_bounds__(512, 4) void k1_attn(
    const float* __restrict__ vf, const float* __restrict__ coords,
    const int* __restrict__ kidx, const void* __restrict__ kmaskv,
    const int* __restrict__ mflag, const float* __restrict__ P,
    const float* __restrict__ wq, const float* __restrict__ bq,
    const float* __restrict__ wk,
    const float* __restrict__ wv, const float* __restrict__ bv,
    const float* __restrict__ wo, const float* __restrict__ bo,
    const float* __restrict__ qpw, const float* __restrict__ qpb,
    const float* __restrict__ kpb,
    float* __restrict__ x1pre, float* __restrict__ stats)
{
  extern __shared__ char smem[];
  u32* WQP = (u32*)smem;          // [c2][i] pack(wq[i][2c2],wq[i][2c2+1]), 8KB
  u32* WKP = WQP + 2048;          // [i2][c] pack(wk[2i2][c],wk[2i2+1][c]), 8KB
  u32* WVP = WKP + 2048;          // [c2][i] 8KB
  u32* WOP = WVP + 2048;          // [c2][i] 8KB
  const int tid = threadIdx.x, wid = tid >> 6, lane = tid & 63;

  for (int t = tid; t < 2048; t += 512) {
    int c2 = t >> 6, i = t & 63;
    WQP[t] = pack2(wq[i*64 + 2*c2], wq[i*64 + 2*c2 + 1]);
    WKP[t] = pack2(wk[2*c2*64 + i], wk[(2*c2+1)*64 + i]);  // here c2 plays i2, i plays c
    WVP[t] = pack2(wv[i*64 + 2*c2], wv[i*64 + 2*c2 + 1]);
    WOP[t] = pack2(wo[i*64 + 2*c2], wo[i*64 + 2*c2 + 1]);
  }
  __syncthreads();

  u32* wbase = (u32*)(smem + 32768) + wid * 1452;
  u32*   KFp = wbase;                   // [32][33] u32 bf16-pairs
  u32*   QKp = wbase + 1056;            // [4][33]  u32 bf16-pairs
  float* S   = (float*)(wbase + 1188);  // [4][66] f32

  const int cl = lane & 31, kh = lane >> 5, hh = lane >> 4;
  const int ca = 2*cl;  // gather channel pair
  const float qp0 = qpw[lane*3], qp1 = qpw[lane*3+1], qp2 = qpw[lane*3+2], qpbl = qpb[lane];
  const float kpbA = kpb[ca], kpbB = kpb[ca+1];
  const float bql = bq[lane], bvl = bv[lane], bol = bo[lane];
  const u32 pvsh = ((lane & 1) ^ 1) << 4;   // PV in-pair select shift
  const int mode4 = mflag[0];
  const u32* km32 = (const u32*)kmaskv;
  const unsigned char* km8 = (const unsigned char*)kmaskv;
  float ssum = 0.f, ssq = 0.f;

  for (int n = blockIdx.x*8 + wid; n < NV; n += 4096) {
    // ---- per-voxel scalars ----
    const float cn0 = coords[n*3], cn1 = coords[n*3+1], cn2 = coords[n*3+2];
    u32 mk;                                           // mask for key cl
    if (mode4) mk = (km32[n*32 + cl] != 0u);
    else       mk = (km8[n*32 + cl]  != 0u);
    const float vfl = vf[(size_t)n*64 + lane];
    const float2 Pn = *(const float2*)(P + (size_t)n*64 + ca);
    const float pnA = Pn.x - kpbA, pnB = Pn.y - kpbB;

    // key indices for this lane's half
    union { int4 v[4]; int s[16]; } iu;
    {
      const int4* kp4 = (const int4*)(kidx + (size_t)n*32 + kh*16);
      iu.v[0] = kp4[0]; iu.v[1] = kp4[1]; iu.v[2] = kp4[2]; iu.v[3] = kp4[3];
    }

    // ---- gather + pos-emb + bf16-pack -> KFp, two batches of 8 keys ----
    #pragma unroll
    for (int b = 0; b < 2; ++b) {
      float2 g[8], p[8];
      #pragma unroll
      for (int k = 0; k < 8; ++k) {
        const size_t off = (size_t)iu.s[b*8+k]*64 + ca;
        g[k] = *(const float2*)(vf + off);
        p[k] = *(const float2*)(P + off);
      }
      #pragma unroll
      for (int k = 0; k < 8; ++k) {
        float kfA = g[k].x + fmaxf(p[k].x - pnA, 0.f);
        float kfB = g[k].y + fmaxf(p[k].y - pnB, 0.f);
        KFp[(kh*16 + b*8 + k)*33 + cl] = cvtpk(kfA, kfB);
      }
    }

    // ---- query = vf + relu(coords @ qpw^T + qpb) ----
    float query = vfl + fmaxf(fmaf(qp0,cn0,fmaf(qp1,cn1,fmaf(qp2,cn2,qpbl))), 0.f);

    // ---- q = Wq query + bq (lane = i), bf16 packed, 2 chains ----
    float qa0 = bql, qa1 = 0.f;
    #pragma unroll
    for (int c2 = 0; c2 < 16; ++c2) {
      u32 w0 = WQP[ c2    *64 + lane];
      u32 w1 = WQP[(c2+16)*64 + lane];
      qa0 = fmaf(bflo(w0), bcastf(query, 2*c2     ), qa0);
      qa0 = fmaf(bfhi(w0), bcastf(query, 2*c2 +  1), qa0);
      qa1 = fmaf(bflo(w1), bcastf(query, 2*c2 + 32), qa1);
      qa1 = fmaf(bfhi(w1), bcastf(query, 2*c2 + 33), qa1);
    }
    const float qacc = qa0 + qa1;

    // ---- qk[h][c] = (Wk_h^T q_h)[c] / 4 (lane = c), 4 chains by head ----
    float qkh0=0.f, qkh1=0.f, qkh2=0.f, qkh3=0.f;
    #pragma unroll
    for (int i2 = 0; i2 < 8; ++i2) {
      u32 w0 = WKP[(i2   )*64+lane];
      u32 w1 = WKP[(i2+ 8)*64+lane];
      u32 w2 = WKP[(i2+16)*64+lane];
      u32 w3 = WKP[(i2+24)*64+lane];
      qkh0 = fmaf(bflo(w0), bcastf(qacc, 2*i2     ), qkh0);
      qkh0 = fmaf(bfhi(w0), bcastf(qacc, 2*i2 +  1), qkh0);
      qkh1 = fmaf(bflo(w1), bcastf(qacc, 2*i2 + 16), qkh1);
      qkh1 = fmaf(bfhi(w1), bcastf(qacc, 2*i2 + 17), qkh1);
      qkh2 = fmaf(bflo(w2), bcastf(qacc, 2*i2 + 32), qkh2);
      qkh2 = fmaf(bfhi(w2), bcastf(qacc, 2*i2 + 33), qkh2);
      qkh3 = fmaf(bflo(w3), bcastf(qacc, 2*i2 + 48), qkh3);
      qkh3 = fmaf(bfhi(w3), bcastf(qacc, 2*i2 + 49), qkh3);
    }
    // pack qk pairs: even lane packs (c, c+1)
    {
      float t0 = __shfl_down(qkh0, 1), t1 = __shfl_down(qkh1, 1);
      float t2 = __shfl_down(qkh2, 1), t3 = __shfl_down(qkh3, 1);
      if ((lane & 1) == 0) {
        int j = lane >> 1;
        QKp[      j] = cvtpk(qkh0*0.25f, t0*0.25f);
        QKp[ 33 + j] = cvtpk(qkh1*0.25f, t1*0.25f);
        QKp[ 66 + j] = cvtpk(qkh2*0.25f, t2*0.25f);
        QKp[ 99 + j] = cvtpk(qkh3*0.25f, t3*0.25f);
      }
    }

    // ---- scores: lane -> key cl, heads kh and kh+2 ----
    float s00=0.f, s01=0.f, s10=0.f, s11=0.f;
    #pragma unroll
    for (int c2 = 0; c2 < 32; ++c2) {
      u32 kp = KFp[cl*33 + c2];
      u32 q0 = QKp[ kh   *33 + c2];
      u32 q1 = QKp[(kh+2)*33 + c2];
      float k0 = bflo(kp), k1 = bfhi(kp);
      s00 = fmaf(bflo(q0), k0, s00); s01 = fmaf(bfhi(q0), k1, s01);
      s10 = fmaf(bflo(q1), k0, s10); s11 = fmaf(bfhi(q1), k1, s11);
    }
    float sc0 = s00 + s01, sc1 = s10 + s11;
    if (mk) { sc0 = -1e30f; sc1 = -1e30f; }

    // ---- softmax over k within each 32-lane half ----
    float m0 = sc0, m1 = sc1;
    #pragma unroll
    for (int off = 16; off; off >>= 1) {
      m0 = fmaxf(m0, __shfl_xor(m0, off));
      m1 = fmaxf(m1, __shfl_xor(m1, off));
    }
    float p0 = __expf(sc0 - m0), p1 = __expf(sc1 - m1);
    float s0 = p0, s1 = p1;
    #pragma unroll
    for (int off = 16; off; off >>= 1) {
      s0 += __shfl_xor(s0, off);
      s1 += __shfl_xor(s1, off);
    }
    const float a0 = p0 / s0, a1 = p1 / s1;  // attn[kh][cl], attn[kh+2][cl]

    // ---- S[h][c] = sum_k attn[h][k]*kf[k][c]  (lane = channel) ----
    float sa0=0.f, sa1=0.f, sa2=0.f, sa3=0.f;
    #pragma unroll
    for (int k2 = 0; k2 < 32; ++k2) {
      u32 kp = KFp[k2*33 + (lane>>1)];
      float kfv = asf((kp << pvsh) & 0xffff0000u);
      sa0 = fmaf(bcastf(a0, k2),    kfv, sa0);
      sa1 = fmaf(bcastf(a0, k2+32), kfv, sa1);
      sa2 = fmaf(bcastf(a1, k2),    kfv, sa2);
      sa3 = fmaf(bcastf(a1, k2+32), kfv, sa3);
    }
    S[       lane] = sa0;
    S[ 66  + lane] = sa1;
    S[132  + lane] = sa2;
    S[198  + lane] = sa3;

    // ---- ctx[i] = Wv_h S[h] + bv  (lane = i, h = i>>4) ----
    float ca0 = bvl, ca1 = 0.f;
    #pragma unroll
    for (int c2 = 0; c2 < 16; ++c2) {
      u32 wp0 = WVP[ c2    *64 + lane];
      u32 wp1 = WVP[(c2+16)*64 + lane];
      ca0 = fmaf(bflo(wp0), S[hh*66 + 2*c2     ], ca0);
      ca0 = fmaf(bfhi(wp0), S[hh*66 + 2*c2 +  1], ca0);
      ca1 = fmaf(bflo(wp1), S[hh*66 + 2*c2 + 32], ca1);
      ca1 = fmaf(bfhi(wp1), S[hh*66 + 2*c2 + 33], ca1);
    }
    const float cacc = ca0 + ca1;

    // ---- attend = Wo ctx + bo ----
    float oa0 = bol, oa1 = 0.f;
    #pragma unroll
    for (int c2 = 0; c2 < 16; ++c2) {
      u32 wp0 = WOP[ c2    *64 + lane];
      u32 wp1 = WOP[(c2+16)*64 + lane];
      oa0 = fmaf(bflo(wp0), bcastf(cacc, 2*c2     ), oa0);
      oa0 = fmaf(bfhi(wp0), bcastf(cacc, 2*c2 +  1), oa0);
      oa1 = fmaf(bflo(wp1), bcastf(cacc, 2*c2 + 32), oa1);
      oa1 = fmaf(bfhi(wp1), bcastf(cacc, 2*c2 + 33), oa1);
    }
    const float aacc = oa0 + oa1;

    float x1 = vfl + aacc;
    x1pre[(size_t)n*64 + lane] = x1;
    ssum += x1; ssq = fmaf(x1, x1, ssq);
  }

  // ---- block-reduce BN1 partials ----
  __syncthreads();
  float* red = (float*)smem;
  red[wid*64 + lane] = ssum;
  red[512 + wid*64 + lane] = ssq;
  __syncthreads();
  if (wid == 0) {
    float t1 = 0.f, t2 = 0.f;
    #pragma unroll
    for (int w = 0; w < 8; ++w) { t1 += red[w*64+lane]; t2 += red[512+w*64+lane]; }
    atomicAdd(&stats[lane], t1);
    atomicAdd(&stats[64+lane], t2);
  }
}

// ---------------------------------------------------------------------------
// K3: x1 = BN1(x1pre); x2pre = x1 + FFN(x1); BN2 partials.
// 256 threads (proven round-2 shape), conflict-free staging, 2-chain ff.
// ---------------------------------------------------------------------------
__global__ __launch_bounds__(256, 2) void k3_ffn(
    const float* __restrict__ x1pre, float* __restrict__ stats,
    const float* __restrict__ g1, const float* __restrict__ b1,
    const float* __restrict__ l1w, const float* __restrict__ l1b,
    const float* __restrict__ l2w, const float* __restrict__ l2b,
    float* __restrict__ x2pre)
{
  extern __shared__ char smem[];
  u16* L1T = (u16*)smem;                      // [c][f] = l1w[f][c]
  u32* L2P = (u32*)(smem + 32768);            // [f2][c] = pack(l2w[c][2f2], l2w[c][2f2+1])
  const int tid = threadIdx.x, wid = tid >> 6, lane = tid & 63;

  // staging: lane index contiguous in the LDS fastest dim -> conflict-free
  {
    const int f = tid;                        // 0..255, lanes contiguous
    #pragma unroll
    for (int c = 0; c < 64; ++c)
      L1T[c*256 + f] = f2bf(l1w[f*64 + c]);
  }
  for (int t = tid; t < 8192; t += 256) {
    int c = t & 63, f2 = t >> 6;              // lanes c contiguous
    float2 w2 = *(const float2*)&l2w[c*256 + f2*2];
    L2P[f2*64 + c] = pack2(w2.x, w2.y);
  }
  __syncthreads();

  const float mean = stats[lane] * (1.f/NV);
  const float var  = stats[64+lane] * (1.f/NV) - mean*mean;
  const float sc   = rsqrtf(var + EPSB) * g1[lane];
  const float sh   = b1[lane] - mean * sc;
  const float4 l1b4 = *(const float4*)&l1b[4*lane];
  const float l2bl = l2b[lane];
  float ssum = 0.f, ssq = 0.f;

  const int stride = gridDim.x << 2;
  for (int n = blockIdx.x*4 + wid; n < NV; n += stride) {
    float x1 = x1pre[(size_t)n*64+lane] * sc + sh;

    // hidden[4*lane+j] = relu(lin1 x1 + b), 4 chains
    float h0 = l1b4.x, h1 = l1b4.y, h2 = l1b4.z, h3 = l1b4.w;
    #pragma unroll
    for (int c = 0; c < 64; ++c) {
      float xv = bcastf(x1, c);
      uint2 wp = *(const uint2*)&L1T[c*256 + 4*lane];
      h0 = fmaf(bflo(wp.x), xv, h0);
      h1 = fmaf(bfhi(wp.x), xv, h1);
      h2 = fmaf(bflo(wp.y), xv, h2);
      h3 = fmaf(bfhi(wp.y), xv, h3);
    }
    h0 = fmaxf(h0,0.f); h1 = fmaxf(h1,0.f); h2 = fmaxf(h2,0.f); h3 = fmaxf(h3,0.f);

    // ff[c] = lin2 @ hidden + b, 2 chains (hidden[f=4l+j] lives in lane l reg hj)
    float ff0 = l2bl, ff1 = 0.f;
    #pragma unroll
    for (int f2 = 0; f2 < 64; ++f2) {
      const int sl0 = f2 >> 1, sl1 = (f2+64) >> 1;
      float a0, b0, a1, b1v;
      if ((f2 & 1) == 0) { a0 = bcastf(h0, sl0); b0 = bcastf(h1, sl0);
                           a1 = bcastf(h0, sl1); b1v = bcastf(h1, sl1); }
      else               { a0 = bcastf(h2, sl0); b0 = bcastf(h3, sl0);
                           a1 = bcastf(h2, sl1); b1v = bcastf(h3, sl1); }
      u32 w0 = L2P[ f2     *64 + lane];
      u32 w1 = L2P[(f2+64) *64 + lane];
      ff0 = fmaf(bflo(w0), a0,  ff0);
      ff0 = fmaf(bfhi(w0), b0,  ff0);
      ff1 = fmaf(bflo(w1), a1,  ff1);
      ff1 = fmaf(bfhi(w1), b1v, ff1);
    }

    float x2 = x1 + (ff0 + ff1);
    x2pre[(size_t)n*64+lane] = x2;
    ssum += x2; ssq = fmaf(x2, x2, ssq);
  }

  __syncthreads();
  float* red = (float*)smem;
  red[wid*64 + lane] = ssum;
  red[256 + wid*64 + lane] = ssq;
  __syncthreads();
  if (wid == 0) {
    float t1 = 0.f, t2 = 0.f;
    #pragma unroll
    for (int w = 0; w < 4; ++w) { t1 += red[w*64+lane]; t2 += red[256+w*64+lane]; }
    atomicAdd(&stats[128+lane], t1);
    atomicAdd(&stats[192+lane], t2);
  }
}

// ---------------------------------------------------------------------------
// K4: x2 = BN2(x2pre); outpre = x2 @ out_w^T + out_b; BN3 partials.
// ---------------------------------------------------------------------------
__global__ __launch_bounds__(256) void k4_out(
    const float* __restrict__ x2pre, float* __restrict__ stats,
    const float* __restrict__ g2, const float* __restrict__ b2,
    const float* __restrict__ outw, const float* __restrict__ outb,
    float* __restrict__ outpre)
{
  extern __shared__ char smem[];
  u16* WT = (u16*)smem;                       // [c][o]
  const int tid = threadIdx.x, wid = tid >> 6, lane = tid & 63;
  for (int t = tid; t < 4096; t += 256) {
    int c = t >> 6, o = t & 63;               // lanes o contiguous -> conflict-free
    WT[c*64+o] = f2bf(outw[o*64 + c]);
  }
  __syncthreads();

  const float mean = stats[128+lane] * (1.f/NV);
  const float var  = stats[192+lane] * (1.f/NV) - mean*mean;
  const float sc   = rsqrtf(var + EPSB) * g2[lane];
  const float sh   = b2[lane] - mean * sc;
  const float obl  = outb[lane];
  float ssum = 0.f, ssq = 0.f;

  const int stride = gridDim.x << 2;
  for (int n = blockIdx.x*4 + wid; n < NV; n += stride) {
    float x2 = x2pre[(size_t)n*64+lane] * sc + sh;
    float a0 = obl, a1 = 0.f;
    #pragma unroll
    for (int c = 0; c < 32; ++c) {
      a0 = fmaf(bf2f(WT[(c   )*64+lane]), bcastf(x2, c   ), a0);
      a1 = fmaf(bf2f(WT[(c+32)*64+lane]), bcastf(x2, c+32), a1);
    }
    float acc = a0 + a1;
    outpre[(size_t)n*64+lane] = acc;
    ssum += acc; ssq = fmaf(acc, acc, ssq);
  }

  __syncthreads();
  float* red = (float*)smem;
  red[wid*64+lane] = ssum;
  red[256 + wid*64 + lane] = ssq;
  __syncthreads();
  if (wid == 0) {
    float t1 = 0.f, t2 = 0.f;
    #pragma unroll
    for (int w = 0; w < 4; ++w) { t1 += red[w*64+lane]; t2 += red[256+w*64+lane]; }
    atomicAdd(&stats[256+lane], t1);
    atomicAdd(&stats[320+lane], t2);
  }
}

// ---------------------------------------------------------------------------
// K5: out = relu(BN3(outpre))
// ---------------------------------------------------------------------------
__global__ __launch_bounds__(256) void k5_fin(
    const float* __restrict__ outpre, const float* __restrict__ stats,
    const float* __restrict__ g3, const float* __restrict__ b3,
    float* __restrict__ out)
{
  const int t = blockIdx.x*256 + threadIdx.x;     // 131072 threads
  const int c0 = (t*4) & 63;
  float sc[4], sh[4];
  #pragma unroll
  for (int j = 0; j < 4; ++j) {
    int c = c0 + j;
    float mean = stats[256+c] * (1.f/NV);
    float var  = stats[320+c] * (1.f/NV) - mean*mean;
    sc[j] = rsqrtf(var + EPSB) * g3[c];
    sh[j] = b3[c] - mean*sc[j];
  }
  for (int i = t; i < NV*16; i += 131072) {
    float4 v = *(const float4*)&outpre[(size_t)i*4];
    v.x = fmaxf(fmaf(v.x, sc[0], sh[0]), 0.f);
    v.y = fmaxf(fmaf(v.y, sc[1], sh[1]), 0.f);
    v.z = fmaxf(fmaf(v.z, sc[2], sh[2]), 0.f);
    v.w = fmaxf(fmaf(v.w, sc[3], sh[3]), 0.f);
    *(float4*)&out[(size_t)i*4] = v;
  }
}

extern "C" void kernel_launch(void* const* d_in, const int* in_sizes, int n_in,
                              void* d_out, int out_size, void* d_ws, size_t ws_size,
                              hipStream_t stream) {
  (void)in_sizes; (void)n_in; (void)out_size; (void)ws_size;
  const float* vf     = (const float*)d_in[0];
  const float* coords = (const float*)d_in[1];
  const int*   kidx   = (const int*)d_in[2];
  const void*  kmask  = d_in[3];
  const float* wq  = (const float*)d_in[4];  const float* bq  = (const float*)d_in[5];
  const float* wk  = (const float*)d_in[6];  /* bk cancels in softmax */
  const float* wv  = (const float*)d_in[8];  const float* bv  = (const float*)d_in[9];
  const float* wo  = (const float*)d_in[10]; const float* bo  = (const float*)d_in[11];
  const float* qpw = (const float*)d_in[12]; const float* qpb = (const float*)d_in[13];
  const float* kpw = (const float*)d_in[14]; const float* kpb = (const float*)d_in[15];
  const float* g1  = (const float*)d_in[16]; const float* b1  = (const float*)d_in[17];
  const float* g2  = (const float*)d_in[18]; const float* b2  = (const float*)d_in[19];
  const float* l1w = (const float*)d_in[20]; const float* l1b = (const float*)d_in[21];
  const float* l2w = (const float*)d_in[22]; const float* l2b = (const float*)d_in[23];
  const float* outw= (const float*)d_in[24]; const float* outb= (const float*)d_in[25];
  const float* g3  = (const float*)d_in[26]; const float* b3  = (const float*)d_in[27];

  float* wsf    = (float*)d_ws;
  float* x1pre  = wsf;                       // [N*64]
  float* x2pre  = wsf + (size_t)NV*64;       // [N*64]; aliases P before K3
  float* P      = x2pre;                     // pos-emb table, dead after K1
  float* outpre = x1pre;                     // alias: x1pre dead after K3
  float* stats  = wsf + (size_t)2*NV*64;     // [384]
  int*   mflag  = (int*)(stats + 384);

  hipMemsetAsync(stats, 0, 384*sizeof(float), stream);

  (void)hipFuncSetAttribute((const void*)k1_attn, hipFuncAttributeMaxDynamicSharedMemorySize, 79232);
  (void)hipFuncSetAttribute((const void*)k3_ffn,  hipFuncAttributeMaxDynamicSharedMemorySize, 65536);

  k0_detect<<<1, 256, 0, stream>>>((const u32*)kmask, mflag);
  k_prep<<<1024, 256, 0, stream>>>(coords, kpw, P);
  k1_attn<<<512, 512, 79232, stream>>>(vf, coords, kidx, kmask, mflag, P,
      wq, bq, wk, wv, bv, wo, bo, qpw, qpb, kpb, x1pre, stats);
  k3_ffn<<<512, 256, 65536, stream>>>(x1pre, stats, g1, b1, l1w, l1b, l2w, l2b, x2pre);
  k4_out<<<2048, 256, 8192, stream>>>(x2pre, stats, g2, b2, outw, outb, outpre);
  k5_fin<<<512, 256, 0, stream>>>(outpre, stats, g3, b3, (float*)d_out);
}

// Round 5
// 887.392 us; speedup vs baseline: 5.7016x; 4.5975x over previous
//
#include <hip/hip_runtime.h>
#include <hip/hip_bf16.h>

#define NV 100000
#define EPSB 1e-5f

typedef unsigned short u16;
typedef unsigned int u32;

__device__ __forceinline__ float bflo(u32 u) {
  union { u32 i; float f; } v; v.i = u << 16; return v.f;
}
__device__ __forceinline__ float bfhi(u32 u) {
  union { u32 i; float f; } v; v.i = u & 0xffff0000u; return v.f;
}
__device__ __forceinline__ float bf2f(u16 u) {
  union { u32 i; float f; } v; v.i = ((u32)u) << 16; return v.f;
}
__device__ __forceinline__ u16 f2bf(float f) {
  union { float f; u32 i; } v; v.f = f;
  u32 r = v.i + 0x7fffu + ((v.i >> 16) & 1u);  // RNE
  return (u16)(r >> 16);
}
__device__ __forceinline__ u32 pack2(float x, float y) {
  return ((u32)f2bf(x)) | (((u32)f2bf(y)) << 16);
}
// hw packed f32->bf16x2 convert (1 VALU op), lo=src0 hi=src1
__device__ __forceinline__ u32 cvtpk(float x, float y) {
  u32 r;
  asm("v_cvt_pk_bf16_f32 %0, %1, %2" : "=v"(r) : "v"(x), "v"(y));
  return r;
}
// uniform broadcast from a lane: v_readlane -> SGPR operand (free in FMA)
__device__ __forceinline__ float bcastf(float v, int l) {
  union { float f; int i; } a; a.f = v;
  union { int i; float f; } b; b.i = __builtin_amdgcn_readlane(a.i, l);
  return b.f;
}
__device__ __forceinline__ float asf(u32 u) {
  union { u32 i; float f; } v; v.i = u; return v.f;
}

// ---------------------------------------------------------------------------
// K0: detect key_mask element width (int32 vs byte-bool).
// ---------------------------------------------------------------------------
__global__ void k0_detect(const u32* __restrict__ km, int* __restrict__ flag) {
  int bad = 0;
  for (int i = threadIdx.x; i < 4096; i += 256) {
    u32 v = km[i];
    bad |= (v != 0u && v != 1u && v != 0x3F800000u) ? 1 : 0;
  }
  unsigned long long m = __ballot(bad != 0);
  __shared__ int sbad[4];
  if ((threadIdx.x & 63) == 0) sbad[threadIdx.x >> 6] = (m != 0ull);
  __syncthreads();
  if (threadIdx.x == 0) flag[0] = !(sbad[0] | sbad[1] | sbad[2] | sbad[3]);
}

// ---------------------------------------------------------------------------
// Kprep: P[m][c] = coords[m,:] . k_pos_w[c,:]
// ---------------------------------------------------------------------------
__global__ __launch_bounds__(256) void k_prep(
    const float* __restrict__ coords, const float* __restrict__ kpw,
    float* __restrict__ P)
{
  const int t = blockIdx.x*256 + threadIdx.x;   // grid 1024 -> 262144 threads
  const int c = t & 63;                          // constant per thread
  const float w0 = kpw[c*3], w1 = kpw[c*3+1], w2 = kpw[c*3+2];
  for (int e = t; e < NV*64; e += 262144) {
    int m = e >> 6;
    float c0 = coords[m*3], c1 = coords[m*3+1], c2 = coords[m*3+2];
    P[e] = fmaf(w0, c0, fmaf(w1, c1, w2*c2));
  }
}

// ---------------------------------------------------------------------------
// K1: gather attention.  512-thread block = 8 waves, one voxel per wave.
// All weights bf16-packed in LDS (32KB) + 8 x 5808B per-wave scratch = 79.2KB
// -> 2 blocks/CU = 4 waves/EU (50% occupancy). (unchanged from round 4 - it
// dropped out of the top-5, i.e. <=~300us)
// ---------------------------------------------------------------------------
__global__ __launch_bounds__(512, 4) void k1_attn(
    const float* __restrict__ vf, const float* __restrict__ coords,
    const int* __restrict__ kidx, const void* __restrict__ kmaskv,
    const int* __restrict__ mflag, const float* __restrict__ P,
    const float* __restrict__ wq, const float* __restrict__ bq,
    const float* __restrict__ wk,
    const float* __restrict__ wv, const float* __restrict__ bv,
    const float* __restrict__ wo, const float* __restrict__ bo,
    const float* __restrict__ qpw, const float* __restrict__ qpb,
    const float* __restrict__ kpb,
    float* __restrict__ x1pre, float* __restrict__ stats)
{
  extern __shared__ char smem[];
  u32* WQP = (u32*)smem;          // [c2][i] pack(wq[i][2c2],wq[i][2c2+1]), 8KB
  u32* WKP = WQP + 2048;          // [i2][c] pack(wk[2i2][c],wk[2i2+1][c]), 8KB
  u32* WVP = WKP + 2048;          // [c2][i] 8KB
  u32* WOP = WVP + 2048;          // [c2][i] 8KB
  const int tid = threadIdx.x, wid = tid >> 6, lane = tid & 63;

  for (int t = tid; t < 2048; t += 512) {
    int c2 = t >> 6, i = t & 63;
    WQP[t] = pack2(wq[i*64 + 2*c2], wq[i*64 + 2*c2 + 1]);
    WKP[t] = pack2(wk[2*c2*64 + i], wk[(2*c2+1)*64 + i]);  // here c2 plays i2, i plays c
    WVP[t] = pack2(wv[i*64 + 2*c2], wv[i*64 + 2*c2 + 1]);
    WOP[t] = pack2(wo[i*64 + 2*c2], wo[i*64 + 2*c2 + 1]);
  }
  __syncthreads();

  u32* wbase = (u32*)(smem + 32768) + wid * 1452;
  u32*   KFp = wbase;                   // [32][33] u32 bf16-pairs
  u32*   QKp = wbase + 1056;            // [4][33]  u32 bf16-pairs
  float* S   = (float*)(wbase + 1188);  // [4][66] f32

  const int cl = lane & 31, kh = lane >> 5, hh = lane >> 4;
  const int ca = 2*cl;  // gather channel pair
  const float qp0 = qpw[lane*3], qp1 = qpw[lane*3+1], qp2 = qpw[lane*3+2], qpbl = qpb[lane];
  const float kpbA = kpb[ca], kpbB = kpb[ca+1];
  const float bql = bq[lane], bvl = bv[lane], bol = bo[lane];
  const u32 pvsh = ((lane & 1) ^ 1) << 4;   // PV in-pair select shift
  const int mode4 = mflag[0];
  const u32* km32 = (const u32*)kmaskv;
  const unsigned char* km8 = (const unsigned char*)kmaskv;
  float ssum = 0.f, ssq = 0.f;

  for (int n = blockIdx.x*8 + wid; n < NV; n += 4096) {
    // ---- per-voxel scalars ----
    const float cn0 = coords[n*3], cn1 = coords[n*3+1], cn2 = coords[n*3+2];
    u32 mk;                                           // mask for key cl
    if (mode4) mk = (km32[n*32 + cl] != 0u);
    else       mk = (km8[n*32 + cl]  != 0u);
    const float vfl = vf[(size_t)n*64 + lane];
    const float2 Pn = *(const float2*)(P + (size_t)n*64 + ca);
    const float pnA = Pn.x - kpbA, pnB = Pn.y - kpbB;

    // key indices for this lane's half
    union { int4 v[4]; int s[16]; } iu;
    {
      const int4* kp4 = (const int4*)(kidx + (size_t)n*32 + kh*16);
      iu.v[0] = kp4[0]; iu.v[1] = kp4[1]; iu.v[2] = kp4[2]; iu.v[3] = kp4[3];
    }

    // ---- gather + pos-emb + bf16-pack -> KFp, two batches of 8 keys ----
    #pragma unroll
    for (int b = 0; b < 2; ++b) {
      float2 g[8], p[8];
      #pragma unroll
      for (int k = 0; k < 8; ++k) {
        const size_t off = (size_t)iu.s[b*8+k]*64 + ca;
        g[k] = *(const float2*)(vf + off);
        p[k] = *(const float2*)(P + off);
      }
      #pragma unroll
      for (int k = 0; k < 8; ++k) {
        float kfA = g[k].x + fmaxf(p[k].x - pnA, 0.f);
        float kfB = g[k].y + fmaxf(p[k].y - pnB, 0.f);
        KFp[(kh*16 + b*8 + k)*33 + cl] = cvtpk(kfA, kfB);
      }
    }

    // ---- query = vf + relu(coords @ qpw^T + qpb) ----
    float query = vfl + fmaxf(fmaf(qp0,cn0,fmaf(qp1,cn1,fmaf(qp2,cn2,qpbl))), 0.f);

    // ---- q = Wq query + bq (lane = i), bf16 packed, 2 chains ----
    float qa0 = bql, qa1 = 0.f;
    #pragma unroll
    for (int c2 = 0; c2 < 16; ++c2) {
      u32 w0 = WQP[ c2    *64 + lane];
      u32 w1 = WQP[(c2+16)*64 + lane];
      qa0 = fmaf(bflo(w0), bcastf(query, 2*c2     ), qa0);
      qa0 = fmaf(bfhi(w0), bcastf(query, 2*c2 +  1), qa0);
      qa1 = fmaf(bflo(w1), bcastf(query, 2*c2 + 32), qa1);
      qa1 = fmaf(bfhi(w1), bcastf(query, 2*c2 + 33), qa1);
    }
    const float qacc = qa0 + qa1;

    // ---- qk[h][c] = (Wk_h^T q_h)[c] / 4 (lane = c), 4 chains by head ----
    float qkh0=0.f, qkh1=0.f, qkh2=0.f, qkh3=0.f;
    #pragma unroll
    for (int i2 = 0; i2 < 8; ++i2) {
      u32 w0 = WKP[(i2   )*64+lane];
      u32 w1 = WKP[(i2+ 8)*64+lane];
      u32 w2 = WKP[(i2+16)*64+lane];
      u32 w3 = WKP[(i2+24)*64+lane];
      qkh0 = fmaf(bflo(w0), bcastf(qacc, 2*i2     ), qkh0);
      qkh0 = fmaf(bfhi(w0), bcastf(qacc, 2*i2 +  1), qkh0);
      qkh1 = fmaf(bflo(w1), bcastf(qacc, 2*i2 + 16), qkh1);
      qkh1 = fmaf(bfhi(w1), bcastf(qacc, 2*i2 + 17), qkh1);
      qkh2 = fmaf(bflo(w2), bcastf(qacc, 2*i2 + 32), qkh2);
      qkh2 = fmaf(bfhi(w2), bcastf(qacc, 2*i2 + 33), qkh2);
      qkh3 = fmaf(bflo(w3), bcastf(qacc, 2*i2 + 48), qkh3);
      qkh3 = fmaf(bfhi(w3), bcastf(qacc, 2*i2 + 49), qkh3);
    }
    // pack qk pairs: even lane packs (c, c+1)
    {
      float t0 = __shfl_down(qkh0, 1), t1 = __shfl_down(qkh1, 1);
      float t2 = __shfl_down(qkh2, 1), t3 = __shfl_down(qkh3, 1);
      if ((lane & 1) == 0) {
        int j = lane >> 1;
        QKp[      j] = cvtpk(qkh0*0.25f, t0*0.25f);
        QKp[ 33 + j] = cvtpk(qkh1*0.25f, t1*0.25f);
        QKp[ 66 + j] = cvtpk(qkh2*0.25f, t2*0.25f);
        QKp[ 99 + j] = cvtpk(qkh3*0.25f, t3*0.25f);
      }
    }

    // ---- scores: lane -> key cl, heads kh and kh+2 ----
    float s00=0.f, s01=0.f, s10=0.f, s11=0.f;
    #pragma unroll
    for (int c2 = 0; c2 < 32; ++c2) {
      u32 kp = KFp[cl*33 + c2];
      u32 q0 = QKp[ kh   *33 + c2];
      u32 q1 = QKp[(kh+2)*33 + c2];
      float k0 = bflo(kp), k1 = bfhi(kp);
      s00 = fmaf(bflo(q0), k0, s00); s01 = fmaf(bfhi(q0), k1, s01);
      s10 = fmaf(bflo(q1), k0, s10); s11 = fmaf(bfhi(q1), k1, s11);
    }
    float sc0 = s00 + s01, sc1 = s10 + s11;
    if (mk) { sc0 = -1e30f; sc1 = -1e30f; }

    // ---- softmax over k within each 32-lane half ----
    float m0 = sc0, m1 = sc1;
    #pragma unroll
    for (int off = 16; off; off >>= 1) {
      m0 = fmaxf(m0, __shfl_xor(m0, off));
      m1 = fmaxf(m1, __shfl_xor(m1, off));
    }
    float p0 = __expf(sc0 - m0), p1 = __expf(sc1 - m1);
    float s0 = p0, s1 = p1;
    #pragma unroll
    for (int off = 16; off; off >>= 1) {
      s0 += __shfl_xor(s0, off);
      s1 += __shfl_xor(s1, off);
    }
    const float a0 = p0 / s0, a1 = p1 / s1;  // attn[kh][cl], attn[kh+2][cl]

    // ---- S[h][c] = sum_k attn[h][k]*kf[k][c]  (lane = channel) ----
    float sa0=0.f, sa1=0.f, sa2=0.f, sa3=0.f;
    #pragma unroll
    for (int k2 = 0; k2 < 32; ++k2) {
      u32 kp = KFp[k2*33 + (lane>>1)];
      float kfv = asf((kp << pvsh) & 0xffff0000u);
      sa0 = fmaf(bcastf(a0, k2),    kfv, sa0);
      sa1 = fmaf(bcastf(a0, k2+32), kfv, sa1);
      sa2 = fmaf(bcastf(a1, k2),    kfv, sa2);
      sa3 = fmaf(bcastf(a1, k2+32), kfv, sa3);
    }
    S[       lane] = sa0;
    S[ 66  + lane] = sa1;
    S[132  + lane] = sa2;
    S[198  + lane] = sa3;

    // ---- ctx[i] = Wv_h S[h] + bv  (lane = i, h = i>>4) ----
    float ca0 = bvl, ca1 = 0.f;
    #pragma unroll
    for (int c2 = 0; c2 < 16; ++c2) {
      u32 wp0 = WVP[ c2    *64 + lane];
      u32 wp1 = WVP[(c2+16)*64 + lane];
      ca0 = fmaf(bflo(wp0), S[hh*66 + 2*c2     ], ca0);
      ca0 = fmaf(bfhi(wp0), S[hh*66 + 2*c2 +  1], ca0);
      ca1 = fmaf(bflo(wp1), S[hh*66 + 2*c2 + 32], ca1);
      ca1 = fmaf(bfhi(wp1), S[hh*66 + 2*c2 + 33], ca1);
    }
    const float cacc = ca0 + ca1;

    // ---- attend = Wo ctx + bo ----
    float oa0 = bol, oa1 = 0.f;
    #pragma unroll
    for (int c2 = 0; c2 < 16; ++c2) {
      u32 wp0 = WOP[ c2    *64 + lane];
      u32 wp1 = WOP[(c2+16)*64 + lane];
      oa0 = fmaf(bflo(wp0), bcastf(cacc, 2*c2     ), oa0);
      oa0 = fmaf(bfhi(wp0), bcastf(cacc, 2*c2 +  1), oa0);
      oa1 = fmaf(bflo(wp1), bcastf(cacc, 2*c2 + 32), oa1);
      oa1 = fmaf(bfhi(wp1), bcastf(cacc, 2*c2 + 33), oa1);
    }
    const float aacc = oa0 + oa1;

    float x1 = vfl + aacc;
    x1pre[(size_t)n*64 + lane] = x1;
    ssum += x1; ssq = fmaf(x1, x1, ssq);
  }

  // ---- block-reduce BN1 partials ----
  __syncthreads();
  float* red = (float*)smem;
  red[wid*64 + lane] = ssum;
  red[512 + wid*64 + lane] = ssq;
  __syncthreads();
  if (wid == 0) {
    float t1 = 0.f, t2 = 0.f;
    #pragma unroll
    for (int w = 0; w < 8; ++w) { t1 += red[w*64+lane]; t2 += red[512+w*64+lane]; }
    atomicAdd(&stats[lane], t1);
    atomicAdd(&stats[64+lane], t2);
  }
}

// ---------------------------------------------------------------------------
// K3: x1 = BN1(x1pre); x2pre = x1 + FFN(x1); BN2 partials.
// EXACT round-2 structure (verbatim): __launch_bounds__(256) with no min-arg,
// original staging, 4-chain hidden, single-load 128-iter ff loop. This
// variant measured <= ~400us with no scratch-spill pathology; rounds 3/4
// restructurings both induced giant spill traffic (6GB / 3.5GB FETCH).
// ---------------------------------------------------------------------------
__global__ __launch_bounds__(256) void k3_ffn(
    const float* __restrict__ x1pre, float* __restrict__ stats,
    const float* __restrict__ g1, const float* __restrict__ b1,
    const float* __restrict__ l1w, const float* __restrict__ l1b,
    const float* __restrict__ l2w, const float* __restrict__ l2b,
    float* __restrict__ x2pre)
{
  extern __shared__ char smem[];
  u16* L1T = (u16*)smem;                      // [c][f]
  u32* L2P = (u32*)(smem + 32768);            // [f2][c], 2 bf16 per u32
  const int tid = threadIdx.x, wid = tid >> 6, lane = tid & 63;

  for (int t = tid; t < 16384; t += 256) {
    int f = t >> 6, c = t & 63;
    L1T[c*256 + f] = f2bf(l1w[t]);
  }
  for (int t = tid; t < 8192; t += 256) {
    int c = t >> 7, f2 = t & 127;
    float2 w2 = *(const float2*)&l2w[c*256 + f2*2];
    L2P[f2*64 + c] = pack2(w2.x, w2.y);
  }
  __syncthreads();

  const float mean = stats[lane] * (1.f/NV);
  const float var  = stats[64+lane] * (1.f/NV) - mean*mean;
  const float sc   = rsqrtf(var + EPSB) * g1[lane];
  const float sh   = b1[lane] - mean * sc;
  const float4 l1b4 = *(const float4*)&l1b[4*lane];
  const float l2bl = l2b[lane];
  float ssum = 0.f, ssq = 0.f;

  const int stride = gridDim.x << 2;
  for (int n = blockIdx.x*4 + wid; n < NV; n += stride) {
    float x1 = x1pre[(size_t)n*64+lane] * sc + sh;

    float h0 = l1b4.x, h1 = l1b4.y, h2 = l1b4.z, h3 = l1b4.w;
    #pragma unroll
    for (int c = 0; c < 64; ++c) {
      float xv = bcastf(x1, c);
      uint2 wp = *(const uint2*)&L1T[c*256 + 4*lane];
      h0 = fmaf(bflo(wp.x), xv, h0);
      h1 = fmaf(bfhi(wp.x), xv, h1);
      h2 = fmaf(bflo(wp.y), xv, h2);
      h3 = fmaf(bfhi(wp.y), xv, h3);
    }
    h0 = fmaxf(h0,0.f); h1 = fmaxf(h1,0.f); h2 = fmaxf(h2,0.f); h3 = fmaxf(h3,0.f);

    float ff = l2bl;
    #pragma unroll
    for (int f2 = 0; f2 < 128; ++f2) {
      const int sl = f2 >> 1;
      float ha, hbv;
      if ((f2 & 1) == 0) { ha = bcastf(h0, sl); hbv = bcastf(h1, sl); }
      else               { ha = bcastf(h2, sl); hbv = bcastf(h3, sl); }
      u32 wp = L2P[f2*64 + lane];
      ff = fmaf(bflo(wp), ha,  ff);
      ff = fmaf(bfhi(wp), hbv, ff);
    }

    float x2 = x1 + ff;
    x2pre[(size_t)n*64+lane] = x2;
    ssum += x2; ssq = fmaf(x2, x2, ssq);
  }

  __syncthreads();
  float* red = (float*)smem;
  red[wid*64+lane] = ssum;
  red[256 + wid*64 + lane] = ssq;
  __syncthreads();
  if (wid == 0) {
    float t1 = 0.f, t2 = 0.f;
    #pragma unroll
    for (int w = 0; w < 4; ++w) { t1 += red[w*64+lane]; t2 += red[256+w*64+lane]; }
    atomicAdd(&stats[128+lane], t1);
    atomicAdd(&stats[192+lane], t2);
  }
}

// ---------------------------------------------------------------------------
// K4: x2 = BN2(x2pre); outpre = x2 @ out_w^T + out_b; BN3 partials.
// ---------------------------------------------------------------------------
__global__ __launch_bounds__(256) void k4_out(
    const float* __restrict__ x2pre, float* __restrict__ stats,
    const float* __restrict__ g2, const float* __restrict__ b2,
    const float* __restrict__ outw, const float* __restrict__ outb,
    float* __restrict__ outpre)
{
  extern __shared__ char smem[];
  u16* WT = (u16*)smem;                       // [c][o]
  const int tid = threadIdx.x, wid = tid >> 6, lane = tid & 63;
  for (int t = tid; t < 4096; t += 256) {
    int c = t >> 6, o = t & 63;               // lanes o contiguous -> conflict-free
    WT[c*64+o] = f2bf(outw[o*64 + c]);
  }
  __syncthreads();

  const float mean = stats[128+lane] * (1.f/NV);
  const float var  = stats[192+lane] * (1.f/NV) - mean*mean;
  const float sc   = rsqrtf(var + EPSB) * g2[lane];
  const float sh   = b2[lane] - mean * sc;
  const float obl  = outb[lane];
  float ssum = 0.f, ssq = 0.f;

  const int stride = gridDim.x << 2;
  for (int n = blockIdx.x*4 + wid; n < NV; n += stride) {
    float x2 = x2pre[(size_t)n*64+lane] * sc + sh;
    float a0 = obl, a1 = 0.f;
    #pragma unroll
    for (int c = 0; c < 32; ++c) {
      a0 = fmaf(bf2f(WT[(c   )*64+lane]), bcastf(x2, c   ), a0);
      a1 = fmaf(bf2f(WT[(c+32)*64+lane]), bcastf(x2, c+32), a1);
    }
    float acc = a0 + a1;
    outpre[(size_t)n*64+lane] = acc;
    ssum += acc; ssq = fmaf(acc, acc, ssq);
  }

  __syncthreads();
  float* red = (float*)smem;
  red[wid*64+lane] = ssum;
  red[256 + wid*64 + lane] = ssq;
  __syncthreads();
  if (wid == 0) {
    float t1 = 0.f, t2 = 0.f;
    #pragma unroll
    for (int w = 0; w < 4; ++w) { t1 += red[w*64+lane]; t2 += red[256+w*64+lane]; }
    atomicAdd(&stats[256+lane], t1);
    atomicAdd(&stats[320+lane], t2);
  }
}

// ---------------------------------------------------------------------------
// K5: out = relu(BN3(outpre))
// ---------------------------------------------------------------------------
__global__ __launch_bounds__(256) void k5_fin(
    const float* __restrict__ outpre, const float* __restrict__ stats,
    const float* __restrict__ g3, const float* __restrict__ b3,
    float* __restrict__ out)
{
  const int t = blockIdx.x*256 + threadIdx.x;     // 131072 threads
  const int c0 = (t*4) & 63;
  float sc[4], sh[4];
  #pragma unroll
  for (int j = 0; j < 4; ++j) {
    int c = c0 + j;
    float mean = stats[256+c] * (1.f/NV);
    float var  = stats[320+c] * (1.f/NV) - mean*mean;
    sc[j] = rsqrtf(var + EPSB) * g3[c];
    sh[j] = b3[c] - mean*sc[j];
  }
  for (int i = t; i < NV*16; i += 131072) {
    float4 v = *(const float4*)&outpre[(size_t)i*4];
    v.x = fmaxf(fmaf(v.x, sc[0], sh[0]), 0.f);
    v.y = fmaxf(fmaf(v.y, sc[1], sh[1]), 0.f);
    v.z = fmaxf(fmaf(v.z, sc[2], sh[2]), 0.f);
    v.w = fmaxf(fmaf(v.w, sc[3], sh[3]), 0.f);
    *(float4*)&out[(size_t)i*4] = v;
  }
}

extern "C" void kernel_launch(void* const* d_in, const int* in_sizes, int n_in,
                              void* d_out, int out_size, void* d_ws, size_t ws_size,
                              hipStream_t stream) {
  (void)in_sizes; (void)n_in; (void)out_size; (void)ws_size;
  const float* vf     = (const float*)d_in[0];
  const float* coords = (const float*)d_in[1];
  const int*   kidx   = (const int*)d_in[2];
  const void*  kmask  = d_in[3];
  const float* wq  = (const float*)d_in[4];  const float* bq  = (const float*)d_in[5];
  const float* wk  = (const float*)d_in[6];  /* bk cancels in softmax */
  const float* wv  = (const float*)d_in[8];  const float* bv  = (const float*)d_in[9];
  const float* wo  = (const float*)d_in[10]; const float* bo  = (const float*)d_in[11];
  const float* qpw = (const float*)d_in[12]; const float* qpb = (const float*)d_in[13];
  const float* kpw = (const float*)d_in[14]; const float* kpb = (const float*)d_in[15];
  const float* g1  = (const float*)d_in[16]; const float* b1  = (const float*)d_in[17];
  const float* g2  = (const float*)d_in[18]; const float* b2  = (const float*)d_in[19];
  const float* l1w = (const float*)d_in[20]; const float* l1b = (const float*)d_in[21];
  const float* l2w = (const float*)d_in[22]; const float* l2b = (const float*)d_in[23];
  const float* outw= (const float*)d_in[24]; const float* outb= (const float*)d_in[25];
  const float* g3  = (const float*)d_in[26]; const float* b3  = (const float*)d_in[27];

  float* wsf    = (float*)d_ws;
  float* x1pre  = wsf;                       // [N*64]
  float* x2pre  = wsf + (size_t)NV*64;       // [N*64]; aliases P before K3
  float* P      = x2pre;                     // pos-emb table, dead after K1
  float* outpre = x1pre;                     // alias: x1pre dead after K3
  float* stats  = wsf + (size_t)2*NV*64;     // [384]
  int*   mflag  = (int*)(stats + 384);

  hipMemsetAsync(stats, 0, 384*sizeof(float), stream);

  (void)hipFuncSetAttribute((const void*)k1_attn, hipFuncAttributeMaxDynamicSharedMemorySize, 79232);
  (void)hipFuncSetAttribute((const void*)k3_ffn,  hipFuncAttributeMaxDynamicSharedMemorySize, 65536);

  k0_detect<<<1, 256, 0, stream>>>((const u32*)kmask, mflag);
  k_prep<<<1024, 256, 0, stream>>>(coords, kpw, P);
  k1_attn<<<512, 512, 79232, stream>>>(vf, coords, kidx, kmask, mflag, P,
      wq, bq, wk, wv, bv, wo, bo, qpw, qpb, kpb, x1pre, stats);
  k3_ffn<<<512, 256, 65536, stream>>>(x1pre, stats, g1, b1, l1w, l1b, l2w, l2b, x2pre);
  k4_out<<<2048, 256, 8192, stream>>>(x2pre, stats, g2, b2, outw, outb, outpre);
  k5_fin<<<512, 256, 0, stream>>>(outpre, stats, g3, b3, (float*)d_out);
}

// Round 6
// 605.413 us; speedup vs baseline: 8.3572x; 1.4658x over previous
//
#include <hip/hip_runtime.h>
#include <hip/hip_bf16.h>

#define NV 100000
#define EPSB 1e-5f

typedef unsigned short u16;
typedef unsigned int u32;

__device__ __forceinline__ float bflo(u32 u) {
  union { u32 i; float f; } v; v.i = u << 16; return v.f;
}
__device__ __forceinline__ float bfhi(u32 u) {
  union { u32 i; float f; } v; v.i = u & 0xffff0000u; return v.f;
}
__device__ __forceinline__ float bf2f(u16 u) {
  union { u32 i; float f; } v; v.i = ((u32)u) << 16; return v.f;
}
__device__ __forceinline__ u16 f2bf(float f) {
  union { float f; u32 i; } v; v.f = f;
  u32 r = v.i + 0x7fffu + ((v.i >> 16) & 1u);  // RNE
  return (u16)(r >> 16);
}
__device__ __forceinline__ u32 pack2(float x, float y) {
  return ((u32)f2bf(x)) | (((u32)f2bf(y)) << 16);
}
// hw packed f32->bf16x2 convert (1 VALU op), lo=src0 hi=src1
__device__ __forceinline__ u32 cvtpk(float x, float y) {
  u32 r;
  asm("v_cvt_pk_bf16_f32 %0, %1, %2" : "=v"(r) : "v"(x), "v"(y));
  return r;
}
// uniform broadcast from a lane: v_readlane -> SGPR operand (free in FMA)
__device__ __forceinline__ float bcastf(float v, int l) {
  union { float f; int i; } a; a.f = v;
  union { int i; float f; } b; b.i = __builtin_amdgcn_readlane(a.i, l);
  return b.f;
}
__device__ __forceinline__ float asf(u32 u) {
  union { u32 i; float f; } v; v.i = u; return v.f;
}

// ---------------------------------------------------------------------------
// K0: detect key_mask element width (int32 vs byte-bool).
// ---------------------------------------------------------------------------
__global__ void k0_detect(const u32* __restrict__ km, int* __restrict__ flag) {
  int bad = 0;
  for (int i = threadIdx.x; i < 4096; i += 256) {
    u32 v = km[i];
    bad |= (v != 0u && v != 1u && v != 0x3F800000u) ? 1 : 0;
  }
  unsigned long long m = __ballot(bad != 0);
  __shared__ int sbad[4];
  if ((threadIdx.x & 63) == 0) sbad[threadIdx.x >> 6] = (m != 0ull);
  __syncthreads();
  if (threadIdx.x == 0) flag[0] = !(sbad[0] | sbad[1] | sbad[2] | sbad[3]);
}

// ---------------------------------------------------------------------------
// Kprep: P[m][c] = coords[m,:] . k_pos_w[c,:]
// ---------------------------------------------------------------------------
__global__ __launch_bounds__(256) void k_prep(
    const float* __restrict__ coords, const float* __restrict__ kpw,
    float* __restrict__ P)
{
  const int t = blockIdx.x*256 + threadIdx.x;   // grid 1024 -> 262144 threads
  const int c = t & 63;                          // constant per thread
  const float w0 = kpw[c*3], w1 = kpw[c*3+1], w2 = kpw[c*3+2];
  for (int e = t; e < NV*64; e += 262144) {
    int m = e >> 6;
    float c0 = coords[m*3], c1 = coords[m*3+1], c2 = coords[m*3+2];
    P[e] = fmaf(w0, c0, fmaf(w1, c1, w2*c2));
  }
}

// ---------------------------------------------------------------------------
// K1: gather attention.  512-thread block = 8 waves, one voxel per wave.
// (unchanged from round 4/5 -- ~250us, 50% occupancy target; next round's
// optimization target)
// ---------------------------------------------------------------------------
__global__ __launch_bounds__(512, 4) void k1_attn(
    const float* __restrict__ vf, const float* __restrict__ coords,
    const int* __restrict__ kidx, const void* __restrict__ kmaskv,
    const int* __restrict__ mflag, const float* __restrict__ P,
    const float* __restrict__ wq, const float* __restrict__ bq,
    const float* __restrict__ wk,
    const float* __restrict__ wv, const float* __restrict__ bv,
    const float* __restrict__ wo, const float* __restrict__ bo,
    const float* __restrict__ qpw, const float* __restrict__ qpb,
    const float* __restrict__ kpb,
    float* __restrict__ x1pre, float* __restrict__ stats)
{
  extern __shared__ char smem[];
  u32* WQP = (u32*)smem;          // [c2][i] pack(wq[i][2c2],wq[i][2c2+1]), 8KB
  u32* WKP = WQP + 2048;          // [i2][c] pack(wk[2i2][c],wk[2i2+1][c]), 8KB
  u32* WVP = WKP + 2048;          // [c2][i] 8KB
  u32* WOP = WVP + 2048;          // [c2][i] 8KB
  const int tid = threadIdx.x, wid = tid >> 6, lane = tid & 63;

  for (int t = tid; t < 2048; t += 512) {
    int c2 = t >> 6, i = t & 63;
    WQP[t] = pack2(wq[i*64 + 2*c2], wq[i*64 + 2*c2 + 1]);
    WKP[t] = pack2(wk[2*c2*64 + i], wk[(2*c2+1)*64 + i]);  // here c2 plays i2, i plays c
    WVP[t] = pack2(wv[i*64 + 2*c2], wv[i*64 + 2*c2 + 1]);
    WOP[t] = pack2(wo[i*64 + 2*c2], wo[i*64 + 2*c2 + 1]);
  }
  __syncthreads();

  u32* wbase = (u32*)(smem + 32768) + wid * 1452;
  u32*   KFp = wbase;                   // [32][33] u32 bf16-pairs
  u32*   QKp = wbase + 1056;            // [4][33]  u32 bf16-pairs
  float* S   = (float*)(wbase + 1188);  // [4][66] f32

  const int cl = lane & 31, kh = lane >> 5, hh = lane >> 4;
  const int ca = 2*cl;  // gather channel pair
  const float qp0 = qpw[lane*3], qp1 = qpw[lane*3+1], qp2 = qpw[lane*3+2], qpbl = qpb[lane];
  const float kpbA = kpb[ca], kpbB = kpb[ca+1];
  const float bql = bq[lane], bvl = bv[lane], bol = bo[lane];
  const u32 pvsh = ((lane & 1) ^ 1) << 4;   // PV in-pair select shift
  const int mode4 = mflag[0];
  const u32* km32 = (const u32*)kmaskv;
  const unsigned char* km8 = (const unsigned char*)kmaskv;
  float ssum = 0.f, ssq = 0.f;

  for (int n = blockIdx.x*8 + wid; n < NV; n += 4096) {
    // ---- per-voxel scalars ----
    const float cn0 = coords[n*3], cn1 = coords[n*3+1], cn2 = coords[n*3+2];
    u32 mk;                                           // mask for key cl
    if (mode4) mk = (km32[n*32 + cl] != 0u);
    else       mk = (km8[n*32 + cl]  != 0u);
    const float vfl = vf[(size_t)n*64 + lane];
    const float2 Pn = *(const float2*)(P + (size_t)n*64 + ca);
    const float pnA = Pn.x - kpbA, pnB = Pn.y - kpbB;

    // key indices for this lane's half
    union { int4 v[4]; int s[16]; } iu;
    {
      const int4* kp4 = (const int4*)(kidx + (size_t)n*32 + kh*16);
      iu.v[0] = kp4[0]; iu.v[1] = kp4[1]; iu.v[2] = kp4[2]; iu.v[3] = kp4[3];
    }

    // ---- gather + pos-emb + bf16-pack -> KFp, two batches of 8 keys ----
    #pragma unroll
    for (int b = 0; b < 2; ++b) {
      float2 g[8], p[8];
      #pragma unroll
      for (int k = 0; k < 8; ++k) {
        const size_t off = (size_t)iu.s[b*8+k]*64 + ca;
        g[k] = *(const float2*)(vf + off);
        p[k] = *(const float2*)(P + off);
      }
      #pragma unroll
      for (int k = 0; k < 8; ++k) {
        float kfA = g[k].x + fmaxf(p[k].x - pnA, 0.f);
        float kfB = g[k].y + fmaxf(p[k].y - pnB, 0.f);
        KFp[(kh*16 + b*8 + k)*33 + cl] = cvtpk(kfA, kfB);
      }
    }

    // ---- query = vf + relu(coords @ qpw^T + qpb) ----
    float query = vfl + fmaxf(fmaf(qp0,cn0,fmaf(qp1,cn1,fmaf(qp2,cn2,qpbl))), 0.f);

    // ---- q = Wq query + bq (lane = i), bf16 packed, 2 chains ----
    float qa0 = bql, qa1 = 0.f;
    #pragma unroll
    for (int c2 = 0; c2 < 16; ++c2) {
      u32 w0 = WQP[ c2    *64 + lane];
      u32 w1 = WQP[(c2+16)*64 + lane];
      qa0 = fmaf(bflo(w0), bcastf(query, 2*c2     ), qa0);
      qa0 = fmaf(bfhi(w0), bcastf(query, 2*c2 +  1), qa0);
      qa1 = fmaf(bflo(w1), bcastf(query, 2*c2 + 32), qa1);
      qa1 = fmaf(bfhi(w1), bcastf(query, 2*c2 + 33), qa1);
    }
    const float qacc = qa0 + qa1;

    // ---- qk[h][c] = (Wk_h^T q_h)[c] / 4 (lane = c), 4 chains by head ----
    float qkh0=0.f, qkh1=0.f, qkh2=0.f, qkh3=0.f;
    #pragma unroll
    for (int i2 = 0; i2 < 8; ++i2) {
      u32 w0 = WKP[(i2   )*64+lane];
      u32 w1 = WKP[(i2+ 8)*64+lane];
      u32 w2 = WKP[(i2+16)*64+lane];
      u32 w3 = WKP[(i2+24)*64+lane];
      qkh0 = fmaf(bflo(w0), bcastf(qacc, 2*i2     ), qkh0);
      qkh0 = fmaf(bfhi(w0), bcastf(qacc, 2*i2 +  1), qkh0);
      qkh1 = fmaf(bflo(w1), bcastf(qacc, 2*i2 + 16), qkh1);
      qkh1 = fmaf(bfhi(w1), bcastf(qacc, 2*i2 + 17), qkh1);
      qkh2 = fmaf(bflo(w2), bcastf(qacc, 2*i2 + 32), qkh2);
      qkh2 = fmaf(bfhi(w2), bcastf(qacc, 2*i2 + 33), qkh2);
      qkh3 = fmaf(bflo(w3), bcastf(qacc, 2*i2 + 48), qkh3);
      qkh3 = fmaf(bfhi(w3), bcastf(qacc, 2*i2 + 49), qkh3);
    }
    // pack qk pairs: even lane packs (c, c+1)
    {
      float t0 = __shfl_down(qkh0, 1), t1 = __shfl_down(qkh1, 1);
      float t2 = __shfl_down(qkh2, 1), t3 = __shfl_down(qkh3, 1);
      if ((lane & 1) == 0) {
        int j = lane >> 1;
        QKp[      j] = cvtpk(qkh0*0.25f, t0*0.25f);
        QKp[ 33 + j] = cvtpk(qkh1*0.25f, t1*0.25f);
        QKp[ 66 + j] = cvtpk(qkh2*0.25f, t2*0.25f);
        QKp[ 99 + j] = cvtpk(qkh3*0.25f, t3*0.25f);
      }
    }

    // ---- scores: lane -> key cl, heads kh and kh+2 ----
    float s00=0.f, s01=0.f, s10=0.f, s11=0.f;
    #pragma unroll
    for (int c2 = 0; c2 < 32; ++c2) {
      u32 kp = KFp[cl*33 + c2];
      u32 q0 = QKp[ kh   *33 + c2];
      u32 q1 = QKp[(kh+2)*33 + c2];
      float k0 = bflo(kp), k1 = bfhi(kp);
      s00 = fmaf(bflo(q0), k0, s00); s01 = fmaf(bfhi(q0), k1, s01);
      s10 = fmaf(bflo(q1), k0, s10); s11 = fmaf(bfhi(q1), k1, s11);
    }
    float sc0 = s00 + s01, sc1 = s10 + s11;
    if (mk) { sc0 = -1e30f; sc1 = -1e30f; }

    // ---- softmax over k within each 32-lane half ----
    float m0 = sc0, m1 = sc1;
    #pragma unroll
    for (int off = 16; off; off >>= 1) {
      m0 = fmaxf(m0, __shfl_xor(m0, off));
      m1 = fmaxf(m1, __shfl_xor(m1, off));
    }
    float p0 = __expf(sc0 - m0), p1 = __expf(sc1 - m1);
    float s0 = p0, s1 = p1;
    #pragma unroll
    for (int off = 16; off; off >>= 1) {
      s0 += __shfl_xor(s0, off);
      s1 += __shfl_xor(s1, off);
    }
    const float a0 = p0 / s0, a1 = p1 / s1;  // attn[kh][cl], attn[kh+2][cl]

    // ---- S[h][c] = sum_k attn[h][k]*kf[k][c]  (lane = channel) ----
    float sa0=0.f, sa1=0.f, sa2=0.f, sa3=0.f;
    #pragma unroll
    for (int k2 = 0; k2 < 32; ++k2) {
      u32 kp = KFp[k2*33 + (lane>>1)];
      float kfv = asf((kp << pvsh) & 0xffff0000u);
      sa0 = fmaf(bcastf(a0, k2),    kfv, sa0);
      sa1 = fmaf(bcastf(a0, k2+32), kfv, sa1);
      sa2 = fmaf(bcastf(a1, k2),    kfv, sa2);
      sa3 = fmaf(bcastf(a1, k2+32), kfv, sa3);
    }
    S[       lane] = sa0;
    S[ 66  + lane] = sa1;
    S[132  + lane] = sa2;
    S[198  + lane] = sa3;

    // ---- ctx[i] = Wv_h S[h] + bv  (lane = i, h = i>>4) ----
    float ca0 = bvl, ca1 = 0.f;
    #pragma unroll
    for (int c2 = 0; c2 < 16; ++c2) {
      u32 wp0 = WVP[ c2    *64 + lane];
      u32 wp1 = WVP[(c2+16)*64 + lane];
      ca0 = fmaf(bflo(wp0), S[hh*66 + 2*c2     ], ca0);
      ca0 = fmaf(bfhi(wp0), S[hh*66 + 2*c2 +  1], ca0);
      ca1 = fmaf(bflo(wp1), S[hh*66 + 2*c2 + 32], ca1);
      ca1 = fmaf(bfhi(wp1), S[hh*66 + 2*c2 + 33], ca1);
    }
    const float cacc = ca0 + ca1;

    // ---- attend = Wo ctx + bo ----
    float oa0 = bol, oa1 = 0.f;
    #pragma unroll
    for (int c2 = 0; c2 < 16; ++c2) {
      u32 wp0 = WOP[ c2    *64 + lane];
      u32 wp1 = WOP[(c2+16)*64 + lane];
      oa0 = fmaf(bflo(wp0), bcastf(cacc, 2*c2     ), oa0);
      oa0 = fmaf(bfhi(wp0), bcastf(cacc, 2*c2 +  1), oa0);
      oa1 = fmaf(bflo(wp1), bcastf(cacc, 2*c2 + 32), oa1);
      oa1 = fmaf(bfhi(wp1), bcastf(cacc, 2*c2 + 33), oa1);
    }
    const float aacc = oa0 + oa1;

    float x1 = vfl + aacc;
    x1pre[(size_t)n*64 + lane] = x1;
    ssum += x1; ssq = fmaf(x1, x1, ssq);
  }

  // ---- block-reduce BN1 partials ----
  __syncthreads();
  float* red = (float*)smem;
  red[wid*64 + lane] = ssum;
  red[512 + wid*64 + lane] = ssq;
  __syncthreads();
  if (wid == 0) {
    float t1 = 0.f, t2 = 0.f;
    #pragma unroll
    for (int w = 0; w < 8; ++w) { t1 += red[w*64+lane]; t2 += red[512+w*64+lane]; }
    atomicAdd(&stats[lane], t1);
    atomicAdd(&stats[64+lane], t2);
  }
}

// ---------------------------------------------------------------------------
// K3: x1 = BN1(x1pre); x2pre = x1 + FFN(x1); BN2 partials.
// 4 voxels per wave: each weight LDS read serves 4 voxels (LDS instrs/voxel
// 192 -> 32). L1T staging verbatim from the proven round-2 kernel; l2w
// re-packed as f-quads (L2Q) so one b64 read yields 4 weights.
// No __launch_bounds__ min-arg (round-3/4 lesson: the VGPR clamp causes
// catastrophic scratch spill).
// ---------------------------------------------------------------------------
__global__ __launch_bounds__(256) void k3_ffn(
    const float* __restrict__ x1pre, float* __restrict__ stats,
    const float* __restrict__ g1, const float* __restrict__ b1,
    const float* __restrict__ l1w, const float* __restrict__ l1b,
    const float* __restrict__ l2w, const float* __restrict__ l2b,
    float* __restrict__ x2pre)
{
  extern __shared__ char smem[];
  u16* L1T = (u16*)smem;                      // [c][f] = l1w[f][c], 32KB
  u32* L2Q = (u32*)(smem + 32768);            // [q][2c+h]: f-quad pack, 32KB
  const int tid = threadIdx.x, wid = tid >> 6, lane = tid & 63;

  for (int t = tid; t < 16384; t += 256) {
    int f = t >> 6, c = t & 63;
    L1T[c*256 + f] = f2bf(l1w[t]);
  }
  for (int t = tid; t < 8192; t += 256) {
    int q = t >> 7, r = t & 127, c = r >> 1, hf = r & 1;
    float2 w2 = *(const float2*)&l2w[c*256 + 4*q + 2*hf];
    L2Q[t] = pack2(w2.x, w2.y);
  }
  __syncthreads();

  const float mean = stats[lane] * (1.f/NV);
  const float var  = stats[64+lane] * (1.f/NV) - mean*mean;
  const float sc   = rsqrtf(var + EPSB) * g1[lane];
  const float sh   = b1[lane] - mean * sc;
  const float4 l1b4 = *(const float4*)&l1b[4*lane];
  const float l2bl = l2b[lane];
  float ssum = 0.f, ssq = 0.f;

  const int stride = gridDim.x << 4;   // 4 waves * 4 voxels per block
  for (int n0 = blockIdx.x*16 + wid*4; n0 < NV; n0 += stride) {
    // NV % 4 == 0 and n0 % 4 == 0 -> n0+3 always valid when n0 < NV
    float xa = x1pre[(size_t) n0   *64+lane] * sc + sh;
    float xb = x1pre[(size_t)(n0+1)*64+lane] * sc + sh;
    float xc = x1pre[(size_t)(n0+2)*64+lane] * sc + sh;
    float xd = x1pre[(size_t)(n0+3)*64+lane] * sc + sh;

    // hidden[4*lane+j] for 4 voxels: 16 independent accumulators
    float h00=l1b4.x, h01=l1b4.y, h02=l1b4.z, h03=l1b4.w;
    float h10=l1b4.x, h11=l1b4.y, h12=l1b4.z, h13=l1b4.w;
    float h20=l1b4.x, h21=l1b4.y, h22=l1b4.z, h23=l1b4.w;
    float h30=l1b4.x, h31=l1b4.y, h32=l1b4.z, h33=l1b4.w;
    #pragma unroll 8
    for (int c = 0; c < 64; ++c) {
      uint2 wp = *(const uint2*)&L1T[c*256 + 4*lane];
      float w0 = bflo(wp.x), w1 = bfhi(wp.x), w2 = bflo(wp.y), w3 = bfhi(wp.y);
      float a0 = bcastf(xa, c), a1 = bcastf(xb, c);
      float a2 = bcastf(xc, c), a3 = bcastf(xd, c);
      h00 = fmaf(w0,a0,h00); h01 = fmaf(w1,a0,h01); h02 = fmaf(w2,a0,h02); h03 = fmaf(w3,a0,h03);
      h10 = fmaf(w0,a1,h10); h11 = fmaf(w1,a1,h11); h12 = fmaf(w2,a1,h12); h13 = fmaf(w3,a1,h13);
      h20 = fmaf(w0,a2,h20); h21 = fmaf(w1,a2,h21); h22 = fmaf(w2,a2,h22); h23 = fmaf(w3,a2,h23);
      h30 = fmaf(w0,a3,h30); h31 = fmaf(w1,a3,h31); h32 = fmaf(w2,a3,h32); h33 = fmaf(w3,a3,h33);
    }
    h00=fmaxf(h00,0.f); h01=fmaxf(h01,0.f); h02=fmaxf(h02,0.f); h03=fmaxf(h03,0.f);
    h10=fmaxf(h10,0.f); h11=fmaxf(h11,0.f); h12=fmaxf(h12,0.f); h13=fmaxf(h13,0.f);
    h20=fmaxf(h20,0.f); h21=fmaxf(h21,0.f); h22=fmaxf(h22,0.f); h23=fmaxf(h23,0.f);
    h30=fmaxf(h30,0.f); h31=fmaxf(h31,0.f); h32=fmaxf(h32,0.f); h33=fmaxf(h33,0.f);

    // ff[c] = lin2 @ hidden + b; hidden f=4q+j lives in lane q, slot j
    float f0 = l2bl, f1 = l2bl, f2v = l2bl, f3 = l2bl;
    #pragma unroll 8
    for (int q = 0; q < 64; ++q) {
      uint2 wp = *(const uint2*)&L2Q[q*128 + 2*lane];
      float w0 = bflo(wp.x), w1 = bfhi(wp.x), w2 = bflo(wp.y), w3 = bfhi(wp.y);
      f0 = fmaf(w0, bcastf(h00,q), f0); f0 = fmaf(w1, bcastf(h01,q), f0);
      f0 = fmaf(w2, bcastf(h02,q), f0); f0 = fmaf(w3, bcastf(h03,q), f0);
      f1 = fmaf(w0, bcastf(h10,q), f1); f1 = fmaf(w1, bcastf(h11,q), f1);
      f1 = fmaf(w2, bcastf(h12,q), f1); f1 = fmaf(w3, bcastf(h13,q), f1);
      f2v = fmaf(w0, bcastf(h20,q), f2v); f2v = fmaf(w1, bcastf(h21,q), f2v);
      f2v = fmaf(w2, bcastf(h22,q), f2v); f2v = fmaf(w3, bcastf(h23,q), f2v);
      f3 = fmaf(w0, bcastf(h30,q), f3); f3 = fmaf(w1, bcastf(h31,q), f3);
      f3 = fmaf(w2, bcastf(h32,q), f3); f3 = fmaf(w3, bcastf(h33,q), f3);
    }

    float y0 = xa + f0, y1 = xb + f1, y2 = xc + f2v, y3 = xd + f3;
    x2pre[(size_t) n0   *64+lane] = y0;
    x2pre[(size_t)(n0+1)*64+lane] = y1;
    x2pre[(size_t)(n0+2)*64+lane] = y2;
    x2pre[(size_t)(n0+3)*64+lane] = y3;
    ssum += (y0 + y1) + (y2 + y3);
    ssq = fmaf(y0,y0, fmaf(y1,y1, fmaf(y2,y2, fmaf(y3,y3, ssq))));
  }

  __syncthreads();
  float* red = (float*)smem;
  red[wid*64+lane] = ssum;
  red[256 + wid*64 + lane] = ssq;
  __syncthreads();
  if (wid == 0) {
    float t1 = 0.f, t2 = 0.f;
    #pragma unroll
    for (int w = 0; w < 4; ++w) { t1 += red[w*64+lane]; t2 += red[256+w*64+lane]; }
    atomicAdd(&stats[128+lane], t1);
    atomicAdd(&stats[192+lane], t2);
  }
}

// ---------------------------------------------------------------------------
// K4: x2 = BN2(x2pre); outpre = x2 @ out_w^T + out_b; BN3 partials.
// 4 voxels per wave + u32-packed weight pairs (8 LDS instr/voxel, was 64).
// ---------------------------------------------------------------------------
__global__ __launch_bounds__(256) void k4_out(
    const float* __restrict__ x2pre, float* __restrict__ stats,
    const float* __restrict__ g2, const float* __restrict__ b2,
    const float* __restrict__ outw, const float* __restrict__ outb,
    float* __restrict__ outpre)
{
  extern __shared__ char smem[];
  u32* WTP = (u32*)smem;                      // [c2][o] = pack(outw[o][2c2],outw[o][2c2+1]), 8KB
  const int tid = threadIdx.x, wid = tid >> 6, lane = tid & 63;
  for (int t = tid; t < 2048; t += 256) {
    int c2 = t >> 6, o = t & 63;              // lanes o contiguous -> conflict-free write
    float2 w2 = *(const float2*)&outw[o*64 + 2*c2];
    WTP[t] = pack2(w2.x, w2.y);
  }
  __syncthreads();

  const float mean = stats[128+lane] * (1.f/NV);
  const float var  = stats[192+lane] * (1.f/NV) - mean*mean;
  const float sc   = rsqrtf(var + EPSB) * g2[lane];
  const float sh   = b2[lane] - mean * sc;
  const float obl  = outb[lane];
  float ssum = 0.f, ssq = 0.f;

  const int stride = gridDim.x << 4;
  for (int n0 = blockIdx.x*16 + wid*4; n0 < NV; n0 += stride) {
    float xa = x2pre[(size_t) n0   *64+lane] * sc + sh;
    float xb = x2pre[(size_t)(n0+1)*64+lane] * sc + sh;
    float xc = x2pre[(size_t)(n0+2)*64+lane] * sc + sh;
    float xd = x2pre[(size_t)(n0+3)*64+lane] * sc + sh;
    float a0 = obl, a1 = obl, a2 = obl, a3 = obl;
    #pragma unroll 8
    for (int c2 = 0; c2 < 32; ++c2) {
      u32 wp = WTP[c2*64 + lane];
      float wl = bflo(wp), wh = bfhi(wp);
      a0 = fmaf(wl, bcastf(xa, 2*c2), a0); a0 = fmaf(wh, bcastf(xa, 2*c2+1), a0);
      a1 = fmaf(wl, bcastf(xb, 2*c2), a1); a1 = fmaf(wh, bcastf(xb, 2*c2+1), a1);
      a2 = fmaf(wl, bcastf(xc, 2*c2), a2); a2 = fmaf(wh, bcastf(xc, 2*c2+1), a2);
      a3 = fmaf(wl, bcastf(xd, 2*c2), a3); a3 = fmaf(wh, bcastf(xd, 2*c2+1), a3);
    }
    outpre[(size_t) n0   *64+lane] = a0;
    outpre[(size_t)(n0+1)*64+lane] = a1;
    outpre[(size_t)(n0+2)*64+lane] = a2;
    outpre[(size_t)(n0+3)*64+lane] = a3;
    ssum += (a0 + a1) + (a2 + a3);
    ssq = fmaf(a0,a0, fmaf(a1,a1, fmaf(a2,a2, fmaf(a3,a3, ssq))));
  }

  __syncthreads();
  float* red = (float*)smem;
  red[wid*64+lane] = ssum;
  red[256 + wid*64 + lane] = ssq;
  __syncthreads();
  if (wid == 0) {
    float t1 = 0.f, t2 = 0.f;
    #pragma unroll
    for (int w = 0; w < 4; ++w) { t1 += red[w*64+lane]; t2 += red[256+w*64+lane]; }
    atomicAdd(&stats[256+lane], t1);
    atomicAdd(&stats[320+lane], t2);
  }
}

// ---------------------------------------------------------------------------
// K5: out = relu(BN3(outpre))
// ---------------------------------------------------------------------------
__global__ __launch_bounds__(256) void k5_fin(
    const float* __restrict__ outpre, const float* __restrict__ stats,
    const float* __restrict__ g3, const float* __restrict__ b3,
    float* __restrict__ out)
{
  const int t = blockIdx.x*256 + threadIdx.x;     // 131072 threads
  const int c0 = (t*4) & 63;
  float sc[4], sh[4];
  #pragma unroll
  for (int j = 0; j < 4; ++j) {
    int c = c0 + j;
    float mean = stats[256+c] * (1.f/NV);
    float var  = stats[320+c] * (1.f/NV) - mean*mean;
    sc[j] = rsqrtf(var + EPSB) * g3[c];
    sh[j] = b3[c] - mean*sc[j];
  }
  for (int i = t; i < NV*16; i += 131072) {
    float4 v = *(const float4*)&outpre[(size_t)i*4];
    v.x = fmaxf(fmaf(v.x, sc[0], sh[0]), 0.f);
    v.y = fmaxf(fmaf(v.y, sc[1], sh[1]), 0.f);
    v.z = fmaxf(fmaf(v.z, sc[2], sh[2]), 0.f);
    v.w = fmaxf(fmaf(v.w, sc[3], sh[3]), 0.f);
    *(float4*)&out[(size_t)i*4] = v;
  }
}

extern "C" void kernel_launch(void* const* d_in, const int* in_sizes, int n_in,
                              void* d_out, int out_size, void* d_ws, size_t ws_size,
                              hipStream_t stream) {
  (void)in_sizes; (void)n_in; (void)out_size; (void)ws_size;
  const float* vf     = (const float*)d_in[0];
  const float* coords = (const float*)d_in[1];
  const int*   kidx   = (const int*)d_in[2];
  const void*  kmask  = d_in[3];
  const float* wq  = (const float*)d_in[4];  const float* bq  = (const float*)d_in[5];
  const float* wk  = (const float*)d_in[6];  /* bk cancels in softmax */
  const float* wv  = (const float*)d_in[8];  const float* bv  = (const float*)d_in[9];
  const float* wo  = (const float*)d_in[10]; const float* bo  = (const float*)d_in[11];
  const float* qpw = (const float*)d_in[12]; const float* qpb = (const float*)d_in[13];
  const float* kpw = (const float*)d_in[14]; const float* kpb = (const float*)d_in[15];
  const float* g1  = (const float*)d_in[16]; const float* b1  = (const float*)d_in[17];
  const float* g2  = (const float*)d_in[18]; const float* b2  = (const float*)d_in[19];
  const float* l1w = (const float*)d_in[20]; const float* l1b = (const float*)d_in[21];
  const float* l2w = (const float*)d_in[22]; const float* l2b = (const float*)d_in[23];
  const float* outw= (const float*)d_in[24]; const float* outb= (const float*)d_in[25];
  const float* g3  = (const float*)d_in[26]; const float* b3  = (const float*)d_in[27];

  float* wsf    = (float*)d_ws;
  float* x1pre  = wsf;                       // [N*64]
  float* x2pre  = wsf + (size_t)NV*64;       // [N*64]; aliases P before K3
  float* P      = x2pre;                     // pos-emb table, dead after K1
  float* outpre = x1pre;                     // alias: x1pre dead after K3
  float* stats  = wsf + (size_t)2*NV*64;     // [384]
  int*   mflag  = (int*)(stats + 384);

  hipMemsetAsync(stats, 0, 384*sizeof(float), stream);

  (void)hipFuncSetAttribute((const void*)k1_attn, hipFuncAttributeMaxDynamicSharedMemorySize, 79232);
  (void)hipFuncSetAttribute((const void*)k3_ffn,  hipFuncAttributeMaxDynamicSharedMemorySize, 65536);

  k0_detect<<<1, 256, 0, stream>>>((const u32*)kmask, mflag);
  k_prep<<<1024, 256, 0, stream>>>(coords, kpw, P);
  k1_attn<<<512, 512, 79232, stream>>>(vf, coords, kidx, kmask, mflag, P,
      wq, bq, wk, wv, bv, wo, bo, qpw, qpb, kpb, x1pre, stats);
  k3_ffn<<<512, 256, 65536, stream>>>(x1pre, stats, g1, b1, l1w, l1b, l2w, l2b, x2pre);
  k4_out<<<1024, 256, 8192, stream>>>(x2pre, stats, g2, b2, outw, outb, outpre);
  k5_fin<<<512, 256, 0, stream>>>(outpre, stats, g3, b3, (float*)d_out);
}

// Round 7
// 527.243 us; speedup vs baseline: 9.5962x; 1.1483x over previous
//
#include <hip/hip_runtime.h>
#include <hip/hip_bf16.h>
#include <hip/hip_fp16.h>

#define NV 100000
#define EPSB 1e-5f

typedef unsigned short u16;
typedef unsigned int u32;
typedef _Float16 half2v __attribute__((ext_vector_type(2)));

__device__ __forceinline__ float bflo(u32 u) {
  union { u32 i; float f; } v; v.i = u << 16; return v.f;
}
__device__ __forceinline__ float bfhi(u32 u) {
  union { u32 i; float f; } v; v.i = u & 0xffff0000u; return v.f;
}
__device__ __forceinline__ u16 f2bf(float f) {
  union { float f; u32 i; } v; v.f = f;
  u32 r = v.i + 0x7fffu + ((v.i >> 16) & 1u);  // RNE
  return (u16)(r >> 16);
}
__device__ __forceinline__ u32 pack2(float x, float y) {
  return ((u32)f2bf(x)) | (((u32)f2bf(y)) << 16);
}
// f32 pair -> packed f16 pair (v_cvt_pkrtz_f16_f32, 1 VALU op)
__device__ __forceinline__ u32 pkh(float x, float y) {
  auto h = __builtin_amdgcn_cvt_pkrtz(x, y);
  union { decltype(h) v; u32 u; } c; c.v = h; return c.u;
}
// dot2: acc += lo(w)*lo(x) + hi(w)*hi(x), f32 accumulate
__device__ __forceinline__ float fdot2(u32 w, u32 x, float acc) {
#if __has_builtin(__builtin_amdgcn_fdot2)
  union { u32 u; half2v h; } a, b; a.u = w; b.u = x;
  return __builtin_amdgcn_fdot2(a.h, b.h, acc, false);
#else
  union { u32 u; __half2 h; } a, b; a.u = w; b.u = x;
  return acc + __low2float(a.h)*__low2float(b.h) + __high2float(a.h)*__high2float(b.h);
#endif
}
// uniform broadcast from a lane: v_readlane -> SGPR operand
__device__ __forceinline__ float bcastf(float v, int l) {
  union { float f; int i; } a; a.f = v;
  union { int i; float f; } b; b.i = __builtin_amdgcn_readlane(a.i, l);
  return b.f;
}
__device__ __forceinline__ u32 bcastu(u32 v, int l) {
  return (u32)__builtin_amdgcn_readlane((int)v, l);
}

// ---------------------------------------------------------------------------
// K0: detect key_mask element width (int32 vs byte-bool).
// ---------------------------------------------------------------------------
__global__ void k0_detect(const u32* __restrict__ km, int* __restrict__ flag) {
  int bad = 0;
  for (int i = threadIdx.x; i < 4096; i += 256) {
    u32 v = km[i];
    bad |= (v != 0u && v != 1u && v != 0x3F800000u) ? 1 : 0;
  }
  unsigned long long m = __ballot(bad != 0);
  __shared__ int sbad[4];
  if ((threadIdx.x & 63) == 0) sbad[threadIdx.x >> 6] = (m != 0ull);
  __syncthreads();
  if (threadIdx.x == 0) flag[0] = !(sbad[0] | sbad[1] | sbad[2] | sbad[3]);
}

// ---------------------------------------------------------------------------
// Kprep: P[m][c] = coords[m,:] . k_pos_w[c,:]
// ---------------------------------------------------------------------------
__global__ __launch_bounds__(256) void k_prep(
    const float* __restrict__ coords, const float* __restrict__ kpw,
    float* __restrict__ P)
{
  const int t = blockIdx.x*256 + threadIdx.x;   // grid 1024 -> 262144 threads
  const int c = t & 63;                          // constant per thread
  const float w0 = kpw[c*3], w1 = kpw[c*3+1], w2 = kpw[c*3+2];
  for (int e = t; e < NV*64; e += 262144) {
    int m = e >> 6;
    float c0 = coords[m*3], c1 = coords[m*3+1], c2 = coords[m*3+2];
    P[e] = fmaf(w0, c0, fmaf(w1, c1, w2*c2));
  }
}

// ---------------------------------------------------------------------------
// K1: gather attention.  512-thread block = 8 waves, one voxel per wave.
// f16 packed math: contractions over channels use v_dot2_f32_f16 (f32 acc);
// PV uses v_pk_fma_f16 (f16 acc, 2 channels/instr). All LDS data f16 pairs.
// Lane roles:
//   gather/pe:  lane -> channels (2cl,2cl+1) of keys kh*16..+15 (cl=lane&31,kh=lane>>5)
//   q/qk/ctx/wo: lane = output channel
//   scores:     lane -> key cl, heads (2hp, 2hp+1), hp=lane>>5
//   PV:         lane -> channel-pair (lane&31), heads (2hp, 2hp+1)
// LDS: 32KB f16 weights + 8 x 5280B per-wave {KFp[32][33], QKp[4][33], SP[4][33]}
// = 75008B -> 2 blocks/CU (4 waves/EU).
// ---------------------------------------------------------------------------
__global__ __launch_bounds__(512, 4) void k1_attn(
    const float* __restrict__ vf, const float* __restrict__ coords,
    const int* __restrict__ kidx, const void* __restrict__ kmaskv,
    const int* __restrict__ mflag, const float* __restrict__ P,
    const float* __restrict__ wq, const float* __restrict__ bq,
    const float* __restrict__ wk,
    const float* __restrict__ wv, const float* __restrict__ bv,
    const float* __restrict__ wo, const float* __restrict__ bo,
    const float* __restrict__ qpw, const float* __restrict__ qpb,
    const float* __restrict__ kpb,
    float* __restrict__ x1pre, float* __restrict__ stats)
{
  extern __shared__ char smem[];
  u32* WQP = (u32*)smem;          // [cp][i]  pkh(wq[i][2cp],wq[i][2cp+1]), 8KB
  u32* WKP = WQP + 2048;          // [ip][c]  pkh(wk[2ip][c],wk[2ip+1][c]), 8KB
  u32* WVP = WKP + 2048;          // [cp][i]  8KB
  u32* WOP = WVP + 2048;          // [cp][j]  8KB
  const int tid = threadIdx.x, wid = tid >> 6, lane = tid & 63;

  for (int t = tid; t < 2048; t += 512) {
    int cp = t >> 6, i = t & 63;
    WQP[t] = pkh(wq[i*64 + 2*cp], wq[i*64 + 2*cp + 1]);
    WKP[t] = pkh(wk[(2*cp)*64 + i], wk[(2*cp+1)*64 + i]);  // cp plays ip, i plays c
    WVP[t] = pkh(wv[i*64 + 2*cp], wv[i*64 + 2*cp + 1]);
    WOP[t] = pkh(wo[i*64 + 2*cp], wo[i*64 + 2*cp + 1]);
  }
  __syncthreads();

  u32* wbase = (u32*)(smem + 32768) + wid * 1320;
  u32* KFp = wbase;            // [32 keys][33] f16 c-pairs
  u32* QKp = wbase + 1056;     // [4 heads][33] f16 c-pairs
  u32* SP  = wbase + 1188;     // [4 heads][33] f16 c-pairs

  const int cl = lane & 31, kh = lane >> 5, hp = lane >> 5, hh = lane >> 4;
  const int ca = 2*cl;  // gather channel pair
  const float qp0 = qpw[lane*3], qp1 = qpw[lane*3+1], qp2 = qpw[lane*3+2], qpbl = qpb[lane];
  const float kpbA = kpb[ca], kpbB = kpb[ca+1];
  const float bql = bq[lane], bvl = bv[lane], bol = bo[lane];
  const int mode4 = mflag[0];
  const u32* km32 = (const u32*)kmaskv;
  const unsigned char* km8 = (const unsigned char*)kmaskv;
  float ssum = 0.f, ssq = 0.f;

  for (int n = blockIdx.x*8 + wid; n < NV; n += 4096) {
    // ---- per-voxel scalars ----
    const float cn0 = coords[n*3], cn1 = coords[n*3+1], cn2 = coords[n*3+2];
    u32 mk;                                           // mask for key cl
    if (mode4) mk = (km32[n*32 + cl] != 0u);
    else       mk = (km8[n*32 + cl]  != 0u);
    const float vfl = vf[(u32)n*64u + (u32)lane];
    const float2 Pn = *(const float2*)(P + (u32)n*64u + (u32)ca);
    const float pnA = Pn.x - kpbA, pnB = Pn.y - kpbB;

    // key indices for this lane's half
    union { int4 v[4]; int s[16]; } iu;
    {
      const int4* kp4 = (const int4*)(kidx + (u32)n*32u + (u32)(kh*16));
      iu.v[0] = kp4[0]; iu.v[1] = kp4[1]; iu.v[2] = kp4[2]; iu.v[3] = kp4[3];
    }

    // ---- gather + pos-emb + f16-pack -> KFp (u32 offsets -> saddr loads) ----
    #pragma unroll
    for (int b = 0; b < 2; ++b) {
      float2 g[8], p[8];
      #pragma unroll
      for (int k = 0; k < 8; ++k) {
        const u32 off = ((u32)iu.s[b*8+k] << 6) + (u32)ca;
        g[k] = *(const float2*)(vf + off);
        p[k] = *(const float2*)(P + off);
      }
      #pragma unroll
      for (int k = 0; k < 8; ++k) {
        float kfA = g[k].x + fmaxf(p[k].x - pnA, 0.f);
        float kfB = g[k].y + fmaxf(p[k].y - pnB, 0.f);
        KFp[(kh*16 + b*8 + k)*33 + cl] = pkh(kfA, kfB);
      }
    }

    // ---- query = vf + relu(coords @ qpw^T + qpb); pack pairs ----
    float query = vfl + fmaxf(fmaf(qp0,cn0,fmaf(qp1,cn1,fmaf(qp2,cn2,qpbl))), 0.f);
    const u32 qpk = pkh(query, __shfl_down(query, 1));   // valid on even lanes

    // ---- q[i] = Wq query + bq (lane = i), dot2, 2 chains ----
    float qa0 = bql, qa1 = 0.f;
    #pragma unroll
    for (int cp = 0; cp < 16; ++cp) {
      qa0 = fdot2(WQP[ cp    *64 + lane], bcastu(qpk, 2*cp     ), qa0);
      qa1 = fdot2(WQP[(cp+16)*64 + lane], bcastu(qpk, 2*cp + 32), qa1);
    }
    const float qacc = (qa0 + qa1) * 0.25f;   // fold 1/sqrt(HD) into q
    const u32 qpk2 = pkh(qacc, __shfl_down(qacc, 1));  // even lanes: (q[2ip],q[2ip+1])

    // ---- qk[h][c] = Wk_h^T q_h (lane = c), dot2, 4 chains by head ----
    float qkh0=0.f, qkh1=0.f, qkh2=0.f, qkh3=0.f;
    #pragma unroll
    for (int p = 0; p < 8; ++p) {
      qkh0 = fdot2(WKP[( p    )*64+lane], bcastu(qpk2, 2*p     ), qkh0);
      qkh1 = fdot2(WKP[( p+ 8 )*64+lane], bcastu(qpk2, 2*p + 16), qkh1);
      qkh2 = fdot2(WKP[( p+16 )*64+lane], bcastu(qpk2, 2*p + 32), qkh2);
      qkh3 = fdot2(WKP[( p+24 )*64+lane], bcastu(qpk2, 2*p + 48), qkh3);
    }
    // pack qk c-pairs: even lane packs (c, c+1)
    {
      float t0 = __shfl_down(qkh0, 1), t1 = __shfl_down(qkh1, 1);
      float t2 = __shfl_down(qkh2, 1), t3 = __shfl_down(qkh3, 1);
      if ((lane & 1) == 0) {
        int j = lane >> 1;
        QKp[      j] = pkh(qkh0, t0);
        QKp[ 33 + j] = pkh(qkh1, t1);
        QKp[ 66 + j] = pkh(qkh2, t2);
        QKp[ 99 + j] = pkh(qkh3, t3);
      }
    }

    // ---- scores: lane -> key cl, heads (2hp, 2hp+1), dot2 f32 acc ----
    float s00=0.f, s01=0.f, s10=0.f, s11=0.f;
    #pragma unroll
    for (int cp = 0; cp < 16; ++cp) {
      u32 kpa = KFp[cl*33 + cp];
      u32 kpb2 = KFp[cl*33 + cp + 16];
      s00 = fdot2(kpa,  QKp[(2*hp  )*33 + cp     ], s00);
      s01 = fdot2(kpb2, QKp[(2*hp  )*33 + cp + 16], s01);
      s10 = fdot2(kpa,  QKp[(2*hp+1)*33 + cp     ], s10);
      s11 = fdot2(kpb2, QKp[(2*hp+1)*33 + cp + 16], s11);
    }
    float sc0 = s00 + s01, sc1 = s10 + s11;
    if (mk) { sc0 = -1e30f; sc1 = -1e30f; }

    // ---- softmax over k within each 32-lane half ----
    float m0 = sc0, m1 = sc1;
    #pragma unroll
    for (int off = 16; off; off >>= 1) {
      m0 = fmaxf(m0, __shfl_xor(m0, off));
      m1 = fmaxf(m1, __shfl_xor(m1, off));
    }
    float p0 = __expf(sc0 - m0), p1 = __expf(sc1 - m1);
    float s0 = p0, s1 = p1;
    #pragma unroll
    for (int off = 16; off; off >>= 1) {
      s0 += __shfl_xor(s0, off);
      s1 += __shfl_xor(s1, off);
    }
    const float a0 = p0 / s0, a1 = p1 / s1;   // attn[2hp][cl], attn[2hp+1][cl]
    const u32 apk = pkh(a0, a1);              // lane k<32: (h0,h1)[k]; k>=32: (h2,h3)[k]

    // ---- PV: lane -> channel-pair j, heads (2hp,2hp+1); pk_fma f16 acc ----
    const int j = lane & 31;
    __half2 accA = __float2half2_rn(0.f), accB = __float2half2_rn(0.f);
    #pragma unroll
    for (int k2 = 0; k2 < 32; ++k2) {
      u32 wlo = bcastu(apk, k2);        // (attn[0][k2], attn[1][k2])
      u32 whi = bcastu(apk, k2 + 32);   // (attn[2][k2], attn[3][k2])
      u32 ws  = hp ? whi : wlo;
      union { u32 u; __half2 h; } kf, w; kf.u = KFp[k2*33 + j]; w.u = ws;
      accA = __hfma2(kf.h, __half2half2(__low2half (w.h)), accA);
      accB = __hfma2(kf.h, __half2half2(__high2half(w.h)), accB);
    }
    { union { __half2 h; u32 u; } ua, ub; ua.h = accA; ub.h = accB;
      SP[(2*hp  )*33 + j] = ua.u;
      SP[(2*hp+1)*33 + j] = ub.u; }

    // ---- ctx[i] = Wv_h S[h] + bv (lane = i, h = i>>4), dot2 ----
    float ca0 = bvl, ca1 = 0.f;
    #pragma unroll
    for (int cp = 0; cp < 16; ++cp) {
      ca0 = fdot2(WVP[ cp    *64 + lane], SP[hh*33 + cp     ], ca0);
      ca1 = fdot2(WVP[(cp+16)*64 + lane], SP[hh*33 + cp + 16], ca1);
    }
    const float cacc = ca0 + ca1;
    const u32 cpk = pkh(cacc, __shfl_down(cacc, 1));  // even lanes: ctx pairs

    // ---- attend = Wo ctx + bo (lane = j), dot2 ----
    float oa0 = bol, oa1 = 0.f;
    #pragma unroll
    for (int cp = 0; cp < 16; ++cp) {
      oa0 = fdot2(WOP[ cp    *64 + lane], bcastu(cpk, 2*cp     ), oa0);
      oa1 = fdot2(WOP[(cp+16)*64 + lane], bcastu(cpk, 2*cp + 32), oa1);
    }
    const float aacc = oa0 + oa1;

    float x1 = vfl + aacc;
    x1pre[(u32)n*64u + (u32)lane] = x1;
    ssum += x1; ssq = fmaf(x1, x1, ssq);
  }

  // ---- block-reduce BN1 partials ----
  __syncthreads();
  float* red = (float*)smem;
  red[wid*64 + lane] = ssum;
  red[512 + wid*64 + lane] = ssq;
  __syncthreads();
  if (wid == 0) {
    float t1 = 0.f, t2 = 0.f;
    #pragma unroll
    for (int w = 0; w < 8; ++w) { t1 += red[w*64+lane]; t2 += red[512+w*64+lane]; }
    atomicAdd(&stats[lane], t1);
    atomicAdd(&stats[64+lane], t2);
  }
}

// ---------------------------------------------------------------------------
// K3: x1 = BN1(x1pre); x2pre = x1 + FFN(x1); BN2 partials. (frozen, round 6)
// ---------------------------------------------------------------------------
__global__ __launch_bounds__(256) void k3_ffn(
    const float* __restrict__ x1pre, float* __restrict__ stats,
    const float* __restrict__ g1, const float* __restrict__ b1,
    const float* __restrict__ l1w, const float* __restrict__ l1b,
    const float* __restrict__ l2w, const float* __restrict__ l2b,
    float* __restrict__ x2pre)
{
  extern __shared__ char smem[];
  u16* L1T = (u16*)smem;                      // [c][f] = l1w[f][c], 32KB
  u32* L2Q = (u32*)(smem + 32768);            // [q][2c+h]: f-quad pack, 32KB
  const int tid = threadIdx.x, wid = tid >> 6, lane = tid & 63;

  for (int t = tid; t < 16384; t += 256) {
    int f = t >> 6, c = t & 63;
    L1T[c*256 + f] = f2bf(l1w[t]);
  }
  for (int t = tid; t < 8192; t += 256) {
    int q = t >> 7, r = t & 127, c = r >> 1, hf = r & 1;
    float2 w2 = *(const float2*)&l2w[c*256 + 4*q + 2*hf];
    L2Q[t] = pack2(w2.x, w2.y);
  }
  __syncthreads();

  const float mean = stats[lane] * (1.f/NV);
  const float var  = stats[64+lane] * (1.f/NV) - mean*mean;
  const float sc   = rsqrtf(var + EPSB) * g1[lane];
  const float sh   = b1[lane] - mean * sc;
  const float4 l1b4 = *(const float4*)&l1b[4*lane];
  const float l2bl = l2b[lane];
  float ssum = 0.f, ssq = 0.f;

  const int stride = gridDim.x << 4;   // 4 waves * 4 voxels per block
  for (int n0 = blockIdx.x*16 + wid*4; n0 < NV; n0 += stride) {
    float xa = x1pre[(size_t) n0   *64+lane] * sc + sh;
    float xb = x1pre[(size_t)(n0+1)*64+lane] * sc + sh;
    float xc = x1pre[(size_t)(n0+2)*64+lane] * sc + sh;
    float xd = x1pre[(size_t)(n0+3)*64+lane] * sc + sh;

    float h00=l1b4.x, h01=l1b4.y, h02=l1b4.z, h03=l1b4.w;
    float h10=l1b4.x, h11=l1b4.y, h12=l1b4.z, h13=l1b4.w;
    float h20=l1b4.x, h21=l1b4.y, h22=l1b4.z, h23=l1b4.w;
    float h30=l1b4.x, h31=l1b4.y, h32=l1b4.z, h33=l1b4.w;
    #pragma unroll 8
    for (int c = 0; c < 64; ++c) {
      uint2 wp = *(const uint2*)&L1T[c*256 + 4*lane];
      float w0 = bflo(wp.x), w1 = bfhi(wp.x), w2 = bflo(wp.y), w3 = bfhi(wp.y);
      float a0 = bcastf(xa, c), a1 = bcastf(xb, c);
      float a2 = bcastf(xc, c), a3 = bcastf(xd, c);
      h00 = fmaf(w0,a0,h00); h01 = fmaf(w1,a0,h01); h02 = fmaf(w2,a0,h02); h03 = fmaf(w3,a0,h03);
      h10 = fmaf(w0,a1,h10); h11 = fmaf(w1,a1,h11); h12 = fmaf(w2,a1,h12); h13 = fmaf(w3,a1,h13);
      h20 = fmaf(w0,a2,h20); h21 = fmaf(w1,a2,h21); h22 = fmaf(w2,a2,h22); h23 = fmaf(w3,a2,h23);
      h30 = fmaf(w0,a3,h30); h31 = fmaf(w1,a3,h31); h32 = fmaf(w2,a3,h32); h33 = fmaf(w3,a3,h33);
    }
    h00=fmaxf(h00,0.f); h01=fmaxf(h01,0.f); h02=fmaxf(h02,0.f); h03=fmaxf(h03,0.f);
    h10=fmaxf(h10,0.f); h11=fmaxf(h11,0.f); h12=fmaxf(h12,0.f); h13=fmaxf(h13,0.f);
    h20=fmaxf(h20,0.f); h21=fmaxf(h21,0.f); h22=fmaxf(h22,0.f); h23=fmaxf(h23,0.f);
    h30=fmaxf(h30,0.f); h31=fmaxf(h31,0.f); h32=fmaxf(h32,0.f); h33=fmaxf(h33,0.f);

    float f0 = l2bl, f1 = l2bl, f2v = l2bl, f3 = l2bl;
    #pragma unroll 8
    for (int q = 0; q < 64; ++q) {
      uint2 wp = *(const uint2*)&L2Q[q*128 + 2*lane];
      float w0 = bflo(wp.x), w1 = bfhi(wp.x), w2 = bflo(wp.y), w3 = bfhi(wp.y);
      f0 = fmaf(w0, bcastf(h00,q), f0); f0 = fmaf(w1, bcastf(h01,q), f0);
      f0 = fmaf(w2, bcastf(h02,q), f0); f0 = fmaf(w3, bcastf(h03,q), f0);
      f1 = fmaf(w0, bcastf(h10,q), f1); f1 = fmaf(w1, bcastf(h11,q), f1);
      f1 = fmaf(w2, bcastf(h12,q), f1); f1 = fmaf(w3, bcastf(h13,q), f1);
      f2v = fmaf(w0, bcastf(h20,q), f2v); f2v = fmaf(w1, bcastf(h21,q), f2v);
      f2v = fmaf(w2, bcastf(h22,q), f2v); f2v = fmaf(w3, bcastf(h23,q), f2v);
      f3 = fmaf(w0, bcastf(h30,q), f3); f3 = fmaf(w1, bcastf(h31,q), f3);
      f3 = fmaf(w2, bcastf(h32,q), f3); f3 = fmaf(w3, bcastf(h33,q), f3);
    }

    float y0 = xa + f0, y1 = xb + f1, y2 = xc + f2v, y3 = xd + f3;
    x2pre[(size_t) n0   *64+lane] = y0;
    x2pre[(size_t)(n0+1)*64+lane] = y1;
    x2pre[(size_t)(n0+2)*64+lane] = y2;
    x2pre[(size_t)(n0+3)*64+lane] = y3;
    ssum += (y0 + y1) + (y2 + y3);
    ssq = fmaf(y0,y0, fmaf(y1,y1, fmaf(y2,y2, fmaf(y3,y3, ssq))));
  }

  __syncthreads();
  float* red = (float*)smem;
  red[wid*64+lane] = ssum;
  red[256 + wid*64 + lane] = ssq;
  __syncthreads();
  if (wid == 0) {
    float t1 = 0.f, t2 = 0.f;
    #pragma unroll
    for (int w = 0; w < 4; ++w) { t1 += red[w*64+lane]; t2 += red[256+w*64+lane]; }
    atomicAdd(&stats[128+lane], t1);
    atomicAdd(&stats[192+lane], t2);
  }
}

// ---------------------------------------------------------------------------
// K4: x2 = BN2(x2pre); outpre = x2 @ out_w^T + out_b; BN3 partials. (frozen)
// ---------------------------------------------------------------------------
__global__ __launch_bounds__(256) void k4_out(
    const float* __restrict__ x2pre, float* __restrict__ stats,
    const float* __restrict__ g2, const float* __restrict__ b2,
    const float* __restrict__ outw, const float* __restrict__ outb,
    float* __restrict__ outpre)
{
  extern __shared__ char smem[];
  u32* WTP = (u32*)smem;                      // [c2][o], 8KB
  const int tid = threadIdx.x, wid = tid >> 6, lane = tid & 63;
  for (int t = tid; t < 2048; t += 256) {
    int c2 = t >> 6, o = t & 63;
    float2 w2 = *(const float2*)&outw[o*64 + 2*c2];
    WTP[t] = pack2(w2.x, w2.y);
  }
  __syncthreads();

  const float mean = stats[128+lane] * (1.f/NV);
  const float var  = stats[192+lane] * (1.f/NV) - mean*mean;
  const float sc   = rsqrtf(var + EPSB) * g2[lane];
  const float sh   = b2[lane] - mean * sc;
  const float obl  = outb[lane];
  float ssum = 0.f, ssq = 0.f;

  const int stride = gridDim.x << 4;
  for (int n0 = blockIdx.x*16 + wid*4; n0 < NV; n0 += stride) {
    float xa = x2pre[(size_t) n0   *64+lane] * sc + sh;
    float xb = x2pre[(size_t)(n0+1)*64+lane] * sc + sh;
    float xc = x2pre[(size_t)(n0+2)*64+lane] * sc + sh;
    float xd = x2pre[(size_t)(n0+3)*64+lane] * sc + sh;
    float a0 = obl, a1 = obl, a2 = obl, a3 = obl;
    #pragma unroll 8
    for (int c2 = 0; c2 < 32; ++c2) {
      u32 wp = WTP[c2*64 + lane];
      float wl = bflo(wp), wh = bfhi(wp);
      a0 = fmaf(wl, bcastf(xa, 2*c2), a0); a0 = fmaf(wh, bcastf(xa, 2*c2+1), a0);
      a1 = fmaf(wl, bcastf(xb, 2*c2), a1); a1 = fmaf(wh, bcastf(xb, 2*c2+1), a1);
      a2 = fmaf(wl, bcastf(xc, 2*c2), a2); a2 = fmaf(wh, bcastf(xc, 2*c2+1), a2);
      a3 = fmaf(wl, bcastf(xd, 2*c2), a3); a3 = fmaf(wh, bcastf(xd, 2*c2+1), a3);
    }
    outpre[(size_t) n0   *64+lane] = a0;
    outpre[(size_t)(n0+1)*64+lane] = a1;
    outpre[(size_t)(n0+2)*64+lane] = a2;
    outpre[(size_t)(n0+3)*64+lane] = a3;
    ssum += (a0 + a1) + (a2 + a3);
    ssq = fmaf(a0,a0, fmaf(a1,a1, fmaf(a2,a2, fmaf(a3,a3, ssq))));
  }

  __syncthreads();
  float* red = (float*)smem;
  red[wid*64+lane] = ssum;
  red[256 + wid*64 + lane] = ssq;
  __syncthreads();
  if (wid == 0) {
    float t1 = 0.f, t2 = 0.f;
    #pragma unroll
    for (int w = 0; w < 4; ++w) { t1 += red[w*64+lane]; t2 += red[256+w*64+lane]; }
    atomicAdd(&stats[256+lane], t1);
    atomicAdd(&stats[320+lane], t2);
  }
}

// ---------------------------------------------------------------------------
// K5: out = relu(BN3(outpre))
// ---------------------------------------------------------------------------
__global__ __launch_bounds__(256) void k5_fin(
    const float* __restrict__ outpre, const float* __restrict__ stats,
    const float* __restrict__ g3, const float* __restrict__ b3,
    float* __restrict__ out)
{
  const int t = blockIdx.x*256 + threadIdx.x;     // 131072 threads
  const int c0 = (t*4) & 63;
  float sc[4], sh[4];
  #pragma unroll
  for (int j = 0; j < 4; ++j) {
    int c = c0 + j;
    float mean = stats[256+c] * (1.f/NV);
    float var  = stats[320+c] * (1.f/NV) - mean*mean;
    sc[j] = rsqrtf(var + EPSB) * g3[c];
    sh[j] = b3[c] - mean*sc[j];
  }
  for (int i = t; i < NV*16; i += 131072) {
    float4 v = *(const float4*)&outpre[(size_t)i*4];
    v.x = fmaxf(fmaf(v.x, sc[0], sh[0]), 0.f);
    v.y = fmaxf(fmaf(v.y, sc[1], sh[1]), 0.f);
    v.z = fmaxf(fmaf(v.z, sc[2], sh[2]), 0.f);
    v.w = fmaxf(fmaf(v.w, sc[3], sh[3]), 0.f);
    *(float4*)&out[(size_t)i*4] = v;
  }
}

extern "C" void kernel_launch(void* const* d_in, const int* in_sizes, int n_in,
                              void* d_out, int out_size, void* d_ws, size_t ws_size,
                              hipStream_t stream) {
  (void)in_sizes; (void)n_in; (void)out_size; (void)ws_size;
  const float* vf     = (const float*)d_in[0];
  const float* coords = (const float*)d_in[1];
  const int*   kidx   = (const int*)d_in[2];
  const void*  kmask  = d_in[3];
  const float* wq  = (const float*)d_in[4];  const float* bq  = (const float*)d_in[5];
  const float* wk  = (const float*)d_in[6];  /* bk cancels in softmax */
  const float* wv  = (const float*)d_in[8];  const float* bv  = (const float*)d_in[9];
  const float* wo  = (const float*)d_in[10]; const float* bo  = (const float*)d_in[11];
  const float* qpw = (const float*)d_in[12]; const float* qpb = (const float*)d_in[13];
  const float* kpw = (const float*)d_in[14]; const float* kpb = (const float*)d_in[15];
  const float* g1  = (const float*)d_in[16]; const float* b1  = (const float*)d_in[17];
  const float* g2  = (const float*)d_in[18]; const float* b2  = (const float*)d_in[19];
  const float* l1w = (const float*)d_in[20]; const float* l1b = (const float*)d_in[21];
  const float* l2w = (const float*)d_in[22]; const float* l2b = (const float*)d_in[23];
  const float* outw= (const float*)d_in[24]; const float* outb= (const float*)d_in[25];
  const float* g3  = (const float*)d_in[26]; const float* b3  = (const float*)d_in[27];

  float* wsf    = (float*)d_ws;
  float* x1pre  = wsf;                       // [N*64]
  float* x2pre  = wsf + (size_t)NV*64;       // [N*64]; aliases P before K3
  float* P      = x2pre;                     // pos-emb table, dead after K1
  float* outpre = x1pre;                     // alias: x1pre dead after K3
  float* stats  = wsf + (size_t)2*NV*64;     // [384]
  int*   mflag  = (int*)(stats + 384);

  hipMemsetAsync(stats, 0, 384*sizeof(float), stream);

  (void)hipFuncSetAttribute((const void*)k1_attn, hipFuncAttributeMaxDynamicSharedMemorySize, 75008);
  (void)hipFuncSetAttribute((const void*)k3_ffn,  hipFuncAttributeMaxDynamicSharedMemorySize, 65536);

  k0_detect<<<1, 256, 0, stream>>>((const u32*)kmask, mflag);
  k_prep<<<1024, 256, 0, stream>>>(coords, kpw, P);
  k1_attn<<<512, 512, 75008, stream>>>(vf, coords, kidx, kmask, mflag, P,
      wq, bq, wk, wv, bv, wo, bo, qpw, qpb, kpb, x1pre, stats);
  k3_ffn<<<512, 256, 65536, stream>>>(x1pre, stats, g1, b1, l1w, l1b, l2w, l2b, x2pre);
  k4_out<<<1024, 256, 8192, stream>>>(x2pre, stats, g2, b2, outw, outb, outpre);
  k5_fin<<<512, 256, 0, stream>>>(outpre, stats, g3, b3, (float*)d_out);
}

// Round 9
// 406.073 us; speedup vs baseline: 12.4597x; 1.2984x over previous
//
#include <hip/hip_runtime.h>
#include <hip/hip_bf16.h>

#define NV 100000
#define EPSB 1e-5f

typedef unsigned short u16;
typedef unsigned int u32;
typedef _Float16 hv2 __attribute__((ext_vector_type(2)));

__device__ __forceinline__ u16 f2bf(float f) {
  union { float f; u32 i; } v; v.f = f;
  u32 r = v.i + 0x7fffu + ((v.i >> 16) & 1u);  // RNE
  return (u16)(r >> 16);
}
// f32 pair -> packed f16 pair (v_cvt_pkrtz_f16_f32, 1 VALU op)
__device__ __forceinline__ u32 pkh(float x, float y) {
  auto h = __builtin_amdgcn_cvt_pkrtz(x, y);
  union { decltype(h) v; u32 u; } c; c.v = h; return c.u;
}
// dot2: acc += lo(w)*lo(x) + hi(w)*hi(x), f32 accumulate
__device__ __forceinline__ float fdot2(u32 w, u32 x, float acc) {
#if __has_builtin(__builtin_amdgcn_fdot2)
  union { u32 u; hv2 h; } a, b; a.u = w; b.u = x;
  return __builtin_amdgcn_fdot2(a.h, b.h, acc, false);
#else
  union { u32 u; hv2 h; } a, b; a.u = w; b.u = x;
  return acc + (float)a.h.x*(float)b.h.x + (float)a.h.y*(float)b.h.y;
#endif
}
__device__ __forceinline__ float bcastf(float v, int l) {
  union { float f; int i; } a; a.f = v;
  union { int i; float f; } b; b.i = __builtin_amdgcn_readlane(a.i, l);
  return b.f;
}
__device__ __forceinline__ u32 bcastu(u32 v, int l) {
  return (u32)__builtin_amdgcn_readlane((int)v, l);
}
__device__ __forceinline__ hv2 as_hv(u32 u) {
  union { u32 u; hv2 h; } c; c.u = u; return c.h;
}
__device__ __forceinline__ u32 as_u32h(hv2 h) {
  union { hv2 h; u32 u; } c; c.h = h; return c.u;
}
__device__ __forceinline__ hv2 hmax2v(hv2 a, hv2 b) {
#if __has_builtin(__builtin_elementwise_max)
  return __builtin_elementwise_max(a, b);
#else
  hv2 r; r.x = a.x > b.x ? a.x : b.x; r.y = a.y > b.y ? a.y : b.y; return r;
#endif
}
__device__ __forceinline__ hv2 hfma2v(hv2 a, hv2 b, hv2 c) {
#if __has_builtin(__builtin_elementwise_fma)
  return __builtin_elementwise_fma(a, b, c);
#else
  return a * b + c;
#endif
}

// ---------------------------------------------------------------------------
// K0: detect key_mask element width (int32 vs byte-bool).
// ---------------------------------------------------------------------------
__global__ void k0_detect(const u32* __restrict__ km, int* __restrict__ flag) {
  int bad = 0;
  for (int i = threadIdx.x; i < 4096; i += 256) {
    u32 v = km[i];
    bad |= (v != 0u && v != 1u && v != 0x3F800000u) ? 1 : 0;
  }
  unsigned long long m = __ballot(bad != 0);
  __shared__ int sbad[4];
  if ((threadIdx.x & 63) == 0) sbad[threadIdx.x >> 6] = (m != 0ull);
  __syncthreads();
  if (threadIdx.x == 0) flag[0] = !(sbad[0] | sbad[1] | sbad[2] | sbad[3]);
}

// ---------------------------------------------------------------------------
// Kprep: VP[m][cp] = { pkh(vf[m][2cp],vf[m][2cp+1]), pkh(P0,P1) } (uint2)
// where P_c = coords[m,:].k_pos_w[c,:].  One 25.6MB f16 table replaces the
// two 25.6MB f32 tables the gather previously touched.
// ---------------------------------------------------------------------------
__global__ __launch_bounds__(256) void k_prep(
    const float* __restrict__ vf, const float* __restrict__ coords,
    const float* __restrict__ kpw, u32* __restrict__ VP)
{
  const int t = blockIdx.x*256 + threadIdx.x;   // grid 2048 -> 524288 threads
  const int cp = t & 31;                         // constant per thread
  const float wa0 = kpw[(2*cp)*3],   wa1 = kpw[(2*cp)*3+1],   wa2 = kpw[(2*cp)*3+2];
  const float wb0 = kpw[(2*cp+1)*3], wb1 = kpw[(2*cp+1)*3+1], wb2 = kpw[(2*cp+1)*3+2];
  for (int e = t; e < NV*32; e += 524288) {
    const int m = e >> 5;
    const float2 v2 = *(const float2*)&vf[(u32)m*64u + 2u*(u32)cp];
    const float c0 = coords[m*3], c1 = coords[m*3+1], c2 = coords[m*3+2];
    const float P0 = fmaf(wa0, c0, fmaf(wa1, c1, wa2*c2));
    const float P1 = fmaf(wb0, c0, fmaf(wb1, c1, wb2*c2));
    uint2 o; o.x = pkh(v2.x, v2.y); o.y = pkh(P0, P1);
    *(uint2*)&VP[(u32)e*2u] = o;
  }
}

// ---------------------------------------------------------------------------
// K1: gather attention.  512-thread block = 8 waves, one voxel per wave.
// Round-8/9: single packed VP gather (16 uint2 loads/lane, packed-f16
// pos-emb in 3 ops) + PV reads splatted attn from LDS (no readlane/select).
// ---------------------------------------------------------------------------
__global__ __launch_bounds__(512, 4) void k1_attn(
    const float* __restrict__ vf, const float* __restrict__ coords,
    const int* __restrict__ kidx, const void* __restrict__ kmaskv,
    const int* __restrict__ mflag, const u32* __restrict__ VP,
    const float* __restrict__ wq, const float* __restrict__ bq,
    const float* __restrict__ wk,
    const float* __restrict__ wv, const float* __restrict__ bv,
    const float* __restrict__ wo, const float* __restrict__ bo,
    const float* __restrict__ qpw, const float* __restrict__ qpb,
    const float* __restrict__ kpb,
    float* __restrict__ x1pre, float* __restrict__ stats)
{
  extern __shared__ char smem[];
  u32* WQP = (u32*)smem;          // [cp][i]  pkh(wq[i][2cp],wq[i][2cp+1]), 8KB
  u32* WKP = WQP + 2048;          // [ip][c]  pkh(wk[2ip][c],wk[2ip+1][c]), 8KB
  u32* WVP = WKP + 2048;          // [cp][i]  8KB
  u32* WOP = WVP + 2048;          // [cp][j]  8KB
  const int tid = threadIdx.x, wid = tid >> 6, lane = tid & 63;

  for (int t = tid; t < 2048; t += 512) {
    int cp = t >> 6, i = t & 63;
    WQP[t] = pkh(wq[i*64 + 2*cp], wq[i*64 + 2*cp + 1]);
    WKP[t] = pkh(wk[(2*cp)*64 + i], wk[(2*cp+1)*64 + i]);  // cp plays ip, i plays c
    WVP[t] = pkh(wv[i*64 + 2*cp], wv[i*64 + 2*cp + 1]);
    WOP[t] = pkh(wo[i*64 + 2*cp], wo[i*64 + 2*cp + 1]);
  }
  __syncthreads();

  u32* wbase = (u32*)(smem + 32768) + wid * 1320;
  u32* KFp = wbase;            // [32 keys][33] f16 c-pairs
  u32* QKp = wbase + 1056;     // [4 heads][33]; aliased as APlo/APhi after scores
  u32* SP  = wbase + 1188;     // [4 heads][33] f16 c-pairs

  const int cl = lane & 31, kh = lane >> 5, hp = lane >> 5, hh = lane >> 4;
  const int ca = 2*cl;  // gather channel pair
  const float qp0 = qpw[lane*3], qp1 = qpw[lane*3+1], qp2 = qpw[lane*3+2], qpbl = qpb[lane];
  const hv2 kpbp = as_hv(pkh(kpb[ca], kpb[ca+1]));
  const hv2 z2 = (hv2)(_Float16)0;
  const float bql = bq[lane], bvl = bv[lane], bol = bo[lane];
  const int mode4 = mflag[0];
  const u32* km32 = (const u32*)kmaskv;
  const unsigned char* km8 = (const unsigned char*)kmaskv;
  float ssum = 0.f, ssq = 0.f;

  for (int n = blockIdx.x*8 + wid; n < NV; n += 4096) {
    // ---- per-voxel scalars ----
    const float cn0 = coords[n*3], cn1 = coords[n*3+1], cn2 = coords[n*3+2];
    u32 mk;                                           // mask for key cl
    if (mode4) mk = (km32[n*32 + cl] != 0u);
    else       mk = (km8[n*32 + cl]  != 0u);
    const float vfl = vf[(u32)n*64u + (u32)lane];
    const uint2 wn = *(const uint2*)&VP[(u32)n*64u + (u32)ca];
    const hv2 pnp = as_hv(wn.y) - kpbp;               // P[n] - kpb (f16 pair)

    // key indices for this lane's half
    union { int4 v[4]; int s[16]; } iu;
    {
      const int4* kp4 = (const int4*)(kidx + (u32)n*32u + (u32)(kh*16));
      iu.v[0] = kp4[0]; iu.v[1] = kp4[1]; iu.v[2] = kp4[2]; iu.v[3] = kp4[3];
    }

    // ---- gather packed (vf,P) + pos-emb (3 pk ops) -> KFp ----
    #pragma unroll
    for (int b = 0; b < 2; ++b) {
      uint2 g[8];
      #pragma unroll
      for (int k = 0; k < 8; ++k) {
        const u32 off = ((u32)iu.s[b*8+k] << 6) + (u32)ca;
        g[k] = *(const uint2*)&VP[off];
      }
      #pragma unroll
      for (int k = 0; k < 8; ++k) {
        hv2 pe = hmax2v(as_hv(g[k].y) - pnp, z2);
        KFp[(kh*16 + b*8 + k)*33 + cl] = as_u32h(as_hv(g[k].x) + pe);
      }
    }

    // ---- query = vf + relu(coords @ qpw^T + qpb); pack pairs ----
    float query = vfl + fmaxf(fmaf(qp0,cn0,fmaf(qp1,cn1,fmaf(qp2,cn2,qpbl))), 0.f);
    const u32 qpk = pkh(query, __shfl_down(query, 1));   // valid on even lanes

    // ---- q[i] = Wq query + bq (lane = i), dot2, 2 chains ----
    float qa0 = bql, qa1 = 0.f;
    #pragma unroll
    for (int cp = 0; cp < 16; ++cp) {
      qa0 = fdot2(WQP[ cp    *64 + lane], bcastu(qpk, 2*cp     ), qa0);
      qa1 = fdot2(WQP[(cp+16)*64 + lane], bcastu(qpk, 2*cp + 32), qa1);
    }
    const float qacc = (qa0 + qa1) * 0.25f;   // fold 1/sqrt(HD) into q
    const u32 qpk2 = pkh(qacc, __shfl_down(qacc, 1));  // even lanes: (q[2ip],q[2ip+1])

    // ---- qk[h][c] = Wk_h^T q_h (lane = c), dot2, 4 chains by head ----
    float qkh0=0.f, qkh1=0.f, qkh2=0.f, qkh3=0.f;
    #pragma unroll
    for (int p = 0; p < 8; ++p) {
      qkh0 = fdot2(WKP[( p    )*64+lane], bcastu(qpk2, 2*p     ), qkh0);
      qkh1 = fdot2(WKP[( p+ 8 )*64+lane], bcastu(qpk2, 2*p + 16), qkh1);
      qkh2 = fdot2(WKP[( p+16 )*64+lane], bcastu(qpk2, 2*p + 32), qkh2);
      qkh3 = fdot2(WKP[( p+24 )*64+lane], bcastu(qpk2, 2*p + 48), qkh3);
    }
    // pack qk c-pairs: even lane packs (c, c+1)
    {
      float t0 = __shfl_down(qkh0, 1), t1 = __shfl_down(qkh1, 1);
      float t2 = __shfl_down(qkh2, 1), t3 = __shfl_down(qkh3, 1);
      if ((lane & 1) == 0) {
        int j = lane >> 1;
        QKp[      j] = pkh(qkh0, t0);
        QKp[ 33 + j] = pkh(qkh1, t1);
        QKp[ 66 + j] = pkh(qkh2, t2);
        QKp[ 99 + j] = pkh(qkh3, t3);
      }
    }

    // ---- scores: lane -> key cl, heads (2hp, 2hp+1), dot2 f32 acc ----
    float s00=0.f, s01=0.f, s10=0.f, s11=0.f;
    #pragma unroll
    for (int cp = 0; cp < 16; ++cp) {
      u32 kpa  = KFp[cl*33 + cp];
      u32 kpb2 = KFp[cl*33 + cp + 16];
      s00 = fdot2(kpa,  QKp[(2*hp  )*33 + cp     ], s00);
      s01 = fdot2(kpb2, QKp[(2*hp  )*33 + cp + 16], s01);
      s10 = fdot2(kpa,  QKp[(2*hp+1)*33 + cp     ], s10);
      s11 = fdot2(kpb2, QKp[(2*hp+1)*33 + cp + 16], s11);
    }
    float sc0 = s00 + s01, sc1 = s10 + s11;
    if (mk) { sc0 = -1e30f; sc1 = -1e30f; }

    // ---- softmax over k within each 32-lane half ----
    float m0 = sc0, m1 = sc1;
    #pragma unroll
    for (int off = 16; off; off >>= 1) {
      m0 = fmaxf(m0, __shfl_xor(m0, off));
      m1 = fmaxf(m1, __shfl_xor(m1, off));
    }
    float p0 = __expf(sc0 - m0), p1 = __expf(sc1 - m1);
    float s0 = p0, s1 = p1;
    #pragma unroll
    for (int off = 16; off; off >>= 1) {
      s0 += __shfl_xor(s0, off);
      s1 += __shfl_xor(s1, off);
    }
    const float a0 = p0 / s0, a1 = p1 / s1;   // attn[2hp][cl], attn[2hp+1][cl]

    // splatted attn -> LDS (alias QKp area; scores reads are done)
    u32* APlo = QKp;        // [64]: lane<32 -> splat attn[0][k] ; lane>=32 -> attn[2][k]
    u32* APhi = QKp + 66;   // [64]: splat attn[1][k] / attn[3][k]
    APlo[lane] = pkh(a0, a0);
    APhi[lane] = pkh(a1, a1);

    // ---- PV: lane -> channel-pair j, heads (2hp,2hp+1); pure LDS+pk_fma ----
    const int j = lane & 31;
    const int ab = hp << 5;
    hv2 accA = z2, accB = z2;
    #pragma unroll
    for (int k2 = 0; k2 < 32; ++k2) {
      hv2 kf = as_hv(KFp[k2*33 + j]);
      accA = hfma2v(kf, as_hv(APlo[ab + k2]), accA);
      accB = hfma2v(kf, as_hv(APhi[ab + k2]), accB);
    }
    SP[(2*hp  )*33 + j] = as_u32h(accA);
    SP[(2*hp+1)*33 + j] = as_u32h(accB);

    // ---- ctx[i] = Wv_h S[h] + bv (lane = i, h = i>>4), dot2 ----
    float ca0 = bvl, ca1 = 0.f;
    #pragma unroll
    for (int cp = 0; cp < 16; ++cp) {
      ca0 = fdot2(WVP[ cp    *64 + lane], SP[hh*33 + cp     ], ca0);
      ca1 = fdot2(WVP[(cp+16)*64 + lane], SP[hh*33 + cp + 16], ca1);
    }
    const float cacc = ca0 + ca1;
    const u32 cpk = pkh(cacc, __shfl_down(cacc, 1));  // even lanes: ctx pairs

    // ---- attend = Wo ctx + bo (lane = j), dot2 ----
    float oa0 = bol, oa1 = 0.f;
    #pragma unroll
    for (int cp = 0; cp < 16; ++cp) {
      oa0 = fdot2(WOP[ cp    *64 + lane], bcastu(cpk, 2*cp     ), oa0);
      oa1 = fdot2(WOP[(cp+16)*64 + lane], bcastu(cpk, 2*cp + 32), oa1);
    }
    const float aacc = oa0 + oa1;

    float x1 = vfl + aacc;
    x1pre[(u32)n*64u + (u32)lane] = x1;
    ssum += x1; ssq = fmaf(x1, x1, ssq);
  }

  // ---- block-reduce BN1 partials ----
  __syncthreads();
  float* red = (float*)smem;
  red[wid*64 + lane] = ssum;
  red[512 + wid*64 + lane] = ssq;
  __syncthreads();
  if (wid == 0) {
    float t1 = 0.f, t2 = 0.f;
    #pragma unroll
    for (int w = 0; w < 8; ++w) { t1 += red[w*64+lane]; t2 += red[512+w*64+lane]; }
    atomicAdd(&stats[lane], t1);
    atomicAdd(&stats[64+lane], t2);
  }
}

// ---------------------------------------------------------------------------
// K3: x1 = BN1(x1pre); x2pre = x1 + FFN(x1); BN2 partials.
// Round-6 macro-structure (4 voxels/wave, 256 thr, no launch_bounds min-arg)
// with f16 dot2 inner math.  L1P [cp][f] read b128 lane-contiguous;
// L2P [fp][c] read b32 lane-contiguous.
// ---------------------------------------------------------------------------
__global__ __launch_bounds__(256) void k3_ffn(
    const float* __restrict__ x1pre, float* __restrict__ stats,
    const float* __restrict__ g1, const float* __restrict__ b1,
    const float* __restrict__ l1w, const float* __restrict__ l1b,
    const float* __restrict__ l2w, const float* __restrict__ l2b,
    float* __restrict__ x2pre)
{
  extern __shared__ char smem[];
  u32* L1P = (u32*)smem;                      // [cp][f]: (l1w[f][2cp],l1w[f][2cp+1]), 32KB
  u32* L2P = (u32*)(smem + 32768);            // [fp][c]: (l2w[c][2fp],l2w[c][2fp+1]), 32KB
  const int tid = threadIdx.x, wid = tid >> 6, lane = tid & 63;

  for (int t = tid; t < 8192; t += 256) {
    int cp = t >> 8, f = t & 255;
    L1P[t] = pkh(l1w[f*64 + 2*cp], l1w[f*64 + 2*cp + 1]);
  }
  for (int t = tid; t < 8192; t += 256) {
    int fp = t >> 6, c = t & 63;
    float2 w2 = *(const float2*)&l2w[c*256 + 2*fp];
    L2P[t] = pkh(w2.x, w2.y);
  }
  __syncthreads();

  const float mean = stats[lane] * (1.f/NV);
  const float var  = stats[64+lane] * (1.f/NV) - mean*mean;
  const float sc   = rsqrtf(var + EPSB) * g1[lane];
  const float sh   = b1[lane] - mean * sc;
  const float4 l1b4 = *(const float4*)&l1b[4*lane];
  const float l2bl = l2b[lane];
  float ssum = 0.f, ssq = 0.f;

  const int stride = gridDim.x << 4;   // 4 waves * 4 voxels per block
  for (int n0 = blockIdx.x*16 + wid*4; n0 < NV; n0 += stride) {
    float xa = x1pre[(size_t) n0   *64+lane] * sc + sh;
    float xb = x1pre[(size_t)(n0+1)*64+lane] * sc + sh;
    float xc = x1pre[(size_t)(n0+2)*64+lane] * sc + sh;
    float xd = x1pre[(size_t)(n0+3)*64+lane] * sc + sh;
    // pack x c-pairs (valid on even lanes)
    const u32 xpa = pkh(xa, __shfl_down(xa,1));
    const u32 xpb = pkh(xb, __shfl_down(xb,1));
    const u32 xpc = pkh(xc, __shfl_down(xc,1));
    const u32 xpd = pkh(xd, __shfl_down(xd,1));

    // hidden[4*lane+j] for 4 voxels: 16 f32 accumulators, dot2 over c-pairs
    float h00=l1b4.x, h01=l1b4.y, h02=l1b4.z, h03=l1b4.w;
    float h10=l1b4.x, h11=l1b4.y, h12=l1b4.z, h13=l1b4.w;
    float h20=l1b4.x, h21=l1b4.y, h22=l1b4.z, h23=l1b4.w;
    float h30=l1b4.x, h31=l1b4.y, h32=l1b4.z, h33=l1b4.w;
    #pragma unroll 8
    for (int cp = 0; cp < 32; ++cp) {
      uint4 w = *(const uint4*)&L1P[cp*256 + 4*lane];
      u32 x0 = bcastu(xpa, 2*cp), x1 = bcastu(xpb, 2*cp);
      u32 x2 = bcastu(xpc, 2*cp), x3 = bcastu(xpd, 2*cp);
      h00=fdot2(w.x,x0,h00); h01=fdot2(w.y,x0,h01); h02=fdot2(w.z,x0,h02); h03=fdot2(w.w,x0,h03);
      h10=fdot2(w.x,x1,h10); h11=fdot2(w.y,x1,h11); h12=fdot2(w.z,x1,h12); h13=fdot2(w.w,x1,h13);
      h20=fdot2(w.x,x2,h20); h21=fdot2(w.y,x2,h21); h22=fdot2(w.z,x2,h22); h23=fdot2(w.w,x2,h23);
      h30=fdot2(w.x,x3,h30); h31=fdot2(w.y,x3,h31); h32=fdot2(w.z,x3,h32); h33=fdot2(w.w,x3,h33);
    }
    h00=fmaxf(h00,0.f); h01=fmaxf(h01,0.f); h02=fmaxf(h02,0.f); h03=fmaxf(h03,0.f);
    h10=fmaxf(h10,0.f); h11=fmaxf(h11,0.f); h12=fmaxf(h12,0.f); h13=fmaxf(h13,0.f);
    h20=fmaxf(h20,0.f); h21=fmaxf(h21,0.f); h22=fmaxf(h22,0.f); h23=fmaxf(h23,0.f);
    h30=fmaxf(h30,0.f); h31=fmaxf(h31,0.f); h32=fmaxf(h32,0.f); h33=fmaxf(h33,0.f);

    // pack h f-pairs: lane q owns f=4q..4q+3 -> pairs (4q,4q+1), (4q+2,4q+3)
    const u32 hpa0 = pkh(h00,h01), hpa1 = pkh(h02,h03);
    const u32 hpb0 = pkh(h10,h11), hpb1 = pkh(h12,h13);
    const u32 hpc0 = pkh(h20,h21), hpc1 = pkh(h22,h23);
    const u32 hpd0 = pkh(h30,h31), hpd1 = pkh(h32,h33);

    // ff[c] = lin2 @ hidden + b: dot2 over f-pairs
    float f0 = l2bl, f1 = l2bl, f2v = l2bl, f3 = l2bl;
    #pragma unroll 8
    for (int i = 0; i < 64; ++i) {
      u32 w0 = L2P[(2*i  )*64 + lane];
      u32 w1 = L2P[(2*i+1)*64 + lane];
      f0  = fdot2(w0, bcastu(hpa0, i), f0);  f0  = fdot2(w1, bcastu(hpa1, i), f0);
      f1  = fdot2(w0, bcastu(hpb0, i), f1);  f1  = fdot2(w1, bcastu(hpb1, i), f1);
      f2v = fdot2(w0, bcastu(hpc0, i), f2v); f2v = fdot2(w1, bcastu(hpc1, i), f2v);
      f3  = fdot2(w0, bcastu(hpd0, i), f3);  f3  = fdot2(w1, bcastu(hpd1, i), f3);
    }

    float y0 = xa + f0, y1 = xb + f1, y2 = xc + f2v, y3 = xd + f3;
    x2pre[(size_t) n0   *64+lane] = y0;
    x2pre[(size_t)(n0+1)*64+lane] = y1;
    x2pre[(size_t)(n0+2)*64+lane] = y2;
    x2pre[(size_t)(n0+3)*64+lane] = y3;
    ssum += (y0 + y1) + (y2 + y3);
    ssq = fmaf(y0,y0, fmaf(y1,y1, fmaf(y2,y2, fmaf(y3,y3, ssq))));
  }

  __syncthreads();
  float* red = (float*)smem;
  red[wid*64+lane] = ssum;
  red[256 + wid*64 + lane] = ssq;
  __syncthreads();
  if (wid == 0) {
    float t1 = 0.f, t2 = 0.f;
    #pragma unroll
    for (int w = 0; w < 4; ++w) { t1 += red[w*64+lane]; t2 += red[256+w*64+lane]; }
    atomicAdd(&stats[128+lane], t1);
    atomicAdd(&stats[192+lane], t2);
  }
}

// ---------------------------------------------------------------------------
// K4: x2 = BN2(x2pre); outpre = x2 @ out_w^T + out_b; BN3 partials.
// 4 voxels/wave, f16 dot2 (4 dot2 + 4 readlane per c-pair iter).
// ---------------------------------------------------------------------------
__global__ __launch_bounds__(256) void k4_out(
    const float* __restrict__ x2pre, float* __restrict__ stats,
    const float* __restrict__ g2, const float* __restrict__ b2,
    const float* __restrict__ outw, const float* __restrict__ outb,
    float* __restrict__ outpre)
{
  extern __shared__ char smem[];
  u32* WTP = (u32*)smem;                      // [cp][o] f16 pairs, 8KB
  const int tid = threadIdx.x, wid = tid >> 6, lane = tid & 63;
  for (int t = tid; t < 2048; t += 256) {
    int cp = t >> 6, o = t & 63;
    WTP[t] = pkh(outw[o*64 + 2*cp], outw[o*64 + 2*cp + 1]);
  }
  __syncthreads();

  const float mean = stats[128+lane] * (1.f/NV);
  const float var  = stats[192+lane] * (1.f/NV) - mean*mean;
  const float sc   = rsqrtf(var + EPSB) * g2[lane];
  const float sh   = b2[lane] - mean * sc;
  const float obl  = outb[lane];
  float ssum = 0.f, ssq = 0.f;

  const int stride = gridDim.x << 4;
  for (int n0 = blockIdx.x*16 + wid*4; n0 < NV; n0 += stride) {
    float xa = x2pre[(size_t) n0   *64+lane] * sc + sh;
    float xb = x2pre[(size_t)(n0+1)*64+lane] * sc + sh;
    float xc = x2pre[(size_t)(n0+2)*64+lane] * sc + sh;
    float xd = x2pre[(size_t)(n0+3)*64+lane] * sc + sh;
    const u32 xpa = pkh(xa, __shfl_down(xa,1));
    const u32 xpb = pkh(xb, __shfl_down(xb,1));
    const u32 xpc = pkh(xc, __shfl_down(xc,1));
    const u32 xpd = pkh(xd, __shfl_down(xd,1));
    float a0 = obl, a1 = obl, a2 = obl, a3 = obl;
    #pragma unroll 8
    for (int cp = 0; cp < 32; ++cp) {
      u32 w = WTP[cp*64 + lane];
      a0 = fdot2(w, bcastu(xpa, 2*cp), a0);
      a1 = fdot2(w, bcastu(xpb, 2*cp), a1);
      a2 = fdot2(w, bcastu(xpc, 2*cp), a2);
      a3 = fdot2(w, bcastu(xpd, 2*cp), a3);
    }
    outpre[(size_t) n0   *64+lane] = a0;
    outpre[(size_t)(n0+1)*64+lane] = a1;
    outpre[(size_t)(n0+2)*64+lane] = a2;
    outpre[(size_t)(n0+3)*64+lane] = a3;
    ssum += (a0 + a1) + (a2 + a3);
    ssq = fmaf(a0,a0, fmaf(a1,a1, fmaf(a2,a2, fmaf(a3,a3, ssq))));
  }

  __syncthreads();
  float* red = (float*)smem;
  red[wid*64+lane] = ssum;
  red[256 + wid*64 + lane] = ssq;
  __syncthreads();
  if (wid == 0) {
    float t1 = 0.f, t2 = 0.f;
    #pragma unroll
    for (int w = 0; w < 4; ++w) { t1 += red[w*64+lane]; t2 += red[256+w*64+lane]; }
    atomicAdd(&stats[256+lane], t1);
    atomicAdd(&stats[320+lane], t2);
  }
}

// ---------------------------------------------------------------------------
// K5: out = relu(BN3(outpre))
// ---------------------------------------------------------------------------
__global__ __launch_bounds__(256) void k5_fin(
    const float* __restrict__ outpre, const float* __restrict__ stats,
    const float* __restrict__ g3, const float* __restrict__ b3,
    float* __restrict__ out)
{
  const int t = blockIdx.x*256 + threadIdx.x;     // 131072 threads
  const int c0 = (t*4) & 63;
  float sc[4], sh[4];
  #pragma unroll
  for (int j = 0; j < 4; ++j) {
    int c = c0 + j;
    float mean = stats[256+c] * (1.f/NV);
    float var  = stats[320+c] * (1.f/NV) - mean*mean;
    sc[j] = rsqrtf(var + EPSB) * g3[c];
    sh[j] = b3[c] - mean*sc[j];
  }
  for (int i = t; i < NV*16; i += 131072) {
    float4 v = *(const float4*)&outpre[(size_t)i*4];
    v.x = fmaxf(fmaf(v.x, sc[0], sh[0]), 0.f);
    v.y = fmaxf(fmaf(v.y, sc[1], sh[1]), 0.f);
    v.z = fmaxf(fmaf(v.z, sc[2], sh[2]), 0.f);
    v.w = fmaxf(fmaf(v.w, sc[3], sh[3]), 0.f);
    *(float4*)&out[(size_t)i*4] = v;
  }
}

extern "C" void kernel_launch(void* const* d_in, const int* in_sizes, int n_in,
                              void* d_out, int out_size, void* d_ws, size_t ws_size,
                              hipStream_t stream) {
  (void)in_sizes; (void)n_in; (void)out_size; (void)ws_size;
  const float* vf     = (const float*)d_in[0];
  const float* coords = (const float*)d_in[1];
  const int*   kidx   = (const int*)d_in[2];
  const void*  kmask  = d_in[3];
  const float* wq  = (const float*)d_in[4];  const float* bq  = (const float*)d_in[5];
  const float* wk  = (const float*)d_in[6];  /* bk cancels in softmax */
  const float* wv  = (const float*)d_in[8];  const float* bv  = (const float*)d_in[9];
  const float* wo  = (const float*)d_in[10]; const float* bo  = (const float*)d_in[11];
  const float* qpw = (const float*)d_in[12]; const float* qpb = (const float*)d_in[13];
  const float* kpw = (const float*)d_in[14]; const float* kpb = (const float*)d_in[15];
  const float* g1  = (const float*)d_in[16]; const float* b1  = (const float*)d_in[17];
  const float* g2  = (const float*)d_in[18]; const float* b2  = (const float*)d_in[19];
  const float* l1w = (const float*)d_in[20]; const float* l1b = (const float*)d_in[21];
  const float* l2w = (const float*)d_in[22]; const float* l2b = (const float*)d_in[23];
  const float* outw= (const float*)d_in[24]; const float* outb= (const float*)d_in[25];
  const float* g3  = (const float*)d_in[26]; const float* b3  = (const float*)d_in[27];

  float* wsf    = (float*)d_ws;
  float* x1pre  = wsf;                       // [N*64]
  float* x2pre  = wsf + (size_t)NV*64;       // [N*64]; aliases VP before K3
  u32*   VP     = (u32*)x2pre;               // packed (vf,P) f16 table, dead after K1
  float* outpre = x1pre;                     // alias: x1pre dead after K3
  float* stats  = wsf + (size_t)2*NV*64;     // [384]
  int*   mflag  = (int*)(stats + 384);

  (void)hipMemsetAsync(stats, 0, 384*sizeof(float), stream);

  (void)hipFuncSetAttribute((const void*)k1_attn, hipFuncAttributeMaxDynamicSharedMemorySize, 75008);
  (void)hipFuncSetAttribute((const void*)k3_ffn,  hipFuncAttributeMaxDynamicSharedMemorySize, 65536);

  k0_detect<<<1, 256, 0, stream>>>((const u32*)kmask, mflag);
  k_prep<<<2048, 256, 0, stream>>>(vf, coords, kpw, VP);
  k1_attn<<<512, 512, 75008, stream>>>(vf, coords, kidx, kmask, mflag, VP,
      wq, bq, wk, wv, bv, wo, bo, qpw, qpb, kpb, x1pre, stats);
  k3_ffn<<<512, 256, 65536, stream>>>(x1pre, stats, g1, b1, l1w, l1b, l2w, l2b, x2pre);
  k4_out<<<1024, 256, 8192, stream>>>(x2pre, stats, g2, b2, outw, outb, outpre);
  k5_fin<<<512, 256, 0, stream>>>(outpre, stats, g3, b3, (float*)d_out);
}